// Round 7
// baseline (2025.153 us; speedup 1.0000x reference)
//
#include <hip/hip_runtime.h>
#include <hip/hip_bf16.h>
#include <math.h>

typedef __bf16 bf16_t;
typedef __bf16 bf16x8 __attribute__((ext_vector_type(8)));
typedef float  floatx4 __attribute__((ext_vector_type(4)));
typedef float  floatx2 __attribute__((ext_vector_type(2)));
typedef unsigned uintx4 __attribute__((ext_vector_type(4)));

constexpr int T_TOK = 4096;
constexpr int HID   = 2048;
constexpr int NH    = 16;
constexpr int DH    = 128;   // head dim
constexpr int CH    = 2048;  // NH*DH

// ---------------- cast fp32 -> bf16 (row-major preserved) ----------------
__global__ __launch_bounds__(256) void cast_to_bf16(const float* __restrict__ in,
                                                    bf16_t* __restrict__ out, int n) {
  int i = (blockIdx.x * 256 + threadIdx.x) * 8;
  if (i >= n) return;
  float4 a = *(const float4*)(in + i);
  float4 b = *(const float4*)(in + i + 4);
  bf16x8 o;
  o[0]=(bf16_t)a.x; o[1]=(bf16_t)a.y; o[2]=(bf16_t)a.z; o[3]=(bf16_t)a.w;
  o[4]=(bf16_t)b.x; o[5]=(bf16_t)b.y; o[6]=(bf16_t)b.z; o[7]=(bf16_t)b.w;
  *(bf16x8*)(out + i) = o;
}

// ---------------- transpose + cast: in fp32 [R,C] -> out bf16 [C,R] ----------------
__global__ __launch_bounds__(256) void transpose_cast(const float* __restrict__ in,
                                                      bf16_t* __restrict__ out, int R, int C) {
  __shared__ float tile[32][33];
  int tx = threadIdx.x & 31;
  int ty = threadIdx.x >> 5;  // 0..7
  int r0 = blockIdx.x * 32;
  int c0 = blockIdx.y * 32;
#pragma unroll
  for (int i = 0; i < 4; i++) {
    int r = ty + i * 8;
    float v = 0.f;
    if (r0 + r < R && c0 + tx < C) v = in[(size_t)(r0 + r) * C + (c0 + tx)];
    tile[r][tx] = v;
  }
  __syncthreads();
#pragma unroll
  for (int i = 0; i < 4; i++) {
    int cr = ty + i * 8;
    if (c0 + cr < C && r0 + tx < R)
      out[(size_t)(c0 + cr) * R + (r0 + tx)] = (bf16_t)tile[tx][cr];
  }
}

// ---------------- bf16 MFMA GEMM: C[M,N] = A[M,K] * Bt[N,K]^T ----------------
template<bool OUT_BF16>
__global__ __launch_bounds__(256) void gemm_bf16(
    const bf16_t* __restrict__ A, int lda,
    const bf16_t* __restrict__ Bt, int ldb,
    void* __restrict__ Cv, int ldc, int M, int N, int K) {
  __shared__ bf16_t sA[128][40];
  __shared__ bf16_t sB[128][40];
  const int tid  = threadIdx.x;
  const int bm0  = blockIdx.x * 128;
  const int bn0  = blockIdx.y * 128;
  const int wave = tid >> 6;
  const int lane = tid & 63;
  const int wm   = (wave & 1) * 64;
  const int wn   = (wave >> 1) * 64;
  const int fm   = lane & 15;
  const int kq   = lane >> 4;

  floatx4 acc[4][4];
#pragma unroll
  for (int mi = 0; mi < 4; mi++)
#pragma unroll
    for (int ni = 0; ni < 4; ni++)
      acc[mi][ni] = (floatx4){0.f, 0.f, 0.f, 0.f};

  const int sr = tid >> 2;
  const int sk = (tid & 3) * 8;
  const bool bval0 = (bn0 + sr) < N;
  const bool bval1 = (bn0 + sr + 64) < N;
  const bf16_t* Ag0 = A + (size_t)(bm0 + sr) * lda + sk;
  const bf16_t* Ag1 = Ag0 + (size_t)64 * lda;
  const bf16_t* Bg0 = Bt + (size_t)(bn0 + sr) * ldb + sk;
  const bf16_t* Bg1 = Bg0 + (size_t)64 * ldb;

  for (int k0 = 0; k0 < K; k0 += 32) {
    float4 a0 = *(const float4*)(Ag0 + k0);
    float4 a1 = *(const float4*)(Ag1 + k0);
    float4 b0 = bval0 ? *(const float4*)(Bg0 + k0) : make_float4(0.f, 0.f, 0.f, 0.f);
    float4 b1 = bval1 ? *(const float4*)(Bg1 + k0) : make_float4(0.f, 0.f, 0.f, 0.f);
    __syncthreads();
    *(float4*)(&sA[sr][sk])      = a0;
    *(float4*)(&sA[sr + 64][sk]) = a1;
    *(float4*)(&sB[sr][sk])      = b0;
    *(float4*)(&sB[sr + 64][sk]) = b1;
    __syncthreads();
    bf16x8 afr[4], bfr[4];
#pragma unroll
    for (int i = 0; i < 4; i++) {
      afr[i] = *(const bf16x8*)(&sA[wm + i * 16 + fm][kq * 8]);
      bfr[i] = *(const bf16x8*)(&sB[wn + i * 16 + fm][kq * 8]);
    }
#pragma unroll
    for (int mi = 0; mi < 4; mi++)
#pragma unroll
      for (int ni = 0; ni < 4; ni++)
        acc[mi][ni] = __builtin_amdgcn_mfma_f32_16x16x32_bf16(afr[mi], bfr[ni], acc[mi][ni], 0, 0, 0);
  }

  const int rr = (lane >> 4) * 4;
#pragma unroll
  for (int mi = 0; mi < 4; mi++) {
#pragma unroll
    for (int r = 0; r < 4; r++) {
      const int row = bm0 + wm + mi * 16 + rr + r;
#pragma unroll
      for (int ni = 0; ni < 4; ni++) {
        const int col = bn0 + wn + ni * 16 + fm;
        if (col < N) {
          if constexpr (OUT_BF16)
            ((bf16_t*)Cv)[(size_t)row * ldc + col] = (bf16_t)acc[mi][ni][r];
          else
            ((float*)Cv)[(size_t)row * ldc + col] = acc[mi][ni][r];
        }
      }
    }
  }
}

// ---------------- conv + silu (+ l2norm) : raw bf16 [T,CH] -> out bf16 [T,CH] ----------------
template<bool L2NORM>
__global__ __launch_bounds__(256) void conv_silu(
    const bf16_t* __restrict__ raw, const float* __restrict__ wconv,
    bf16_t* __restrict__ out) {
  const int t   = blockIdx.x;
  const int tid = threadIdx.x;
  const int c0  = tid * 8;

  float w[8][4];
#pragma unroll
  for (int j = 0; j < 8; j++) {
    float4 t0 = *(const float4*)(wconv + (size_t)(c0 + j) * 4);
    w[j][0] = t0.x; w[j][1] = t0.y; w[j][2] = t0.z; w[j][3] = t0.w;
  }
  float a[8] = {};
#pragma unroll
  for (int i = 0; i < 4; i++) {
    int tr = t - 3 + i;
    if (tr < 0) continue;
    bf16x8 xr = *(const bf16x8*)(raw + (size_t)tr * CH + c0);
#pragma unroll
    for (int j = 0; j < 8; j++) a[j] += w[j][i] * (float)xr[j];
  }
  float s = 0.f;
#pragma unroll
  for (int j = 0; j < 8; j++) {
    a[j] = a[j] / (1.f + expf(-a[j]));  // silu
    s += a[j] * a[j];
  }
  float rs = 1.f;
  if constexpr (L2NORM) {
#pragma unroll
    for (int m = 1; m < 16; m <<= 1) s += __shfl_xor(s, m);
    rs = rsqrtf(s + 1e-6f);
  }
  bf16x8 r;
#pragma unroll
  for (int j = 0; j < 8; j++) r[j] = (bf16_t)(a[j] * rs);
  *(bf16x8*)(out + (size_t)t * CH + c0) = r;
}

// ---------------- gamma: now writes g = -a*softplus (LOG decay, not exp) + beta sigmoid ----------------
__global__ __launch_bounds__(256) void gamma_beta(
    float* __restrict__ f_gam, const float* __restrict__ dt_bias,
    const float* __restrict__ A_log, float* __restrict__ beta_io) {
  const int t   = blockIdx.x;
  const int tid = threadIdx.x;
  const int c0  = tid * 8;
  const int h   = c0 >> 7;
  const float a_h = expf(A_log[h]);
  const size_t o0 = (size_t)t * CH + c0;
  float fv[8], db[8];
  { float4 f0 = *(const float4*)(f_gam + o0);   float4 f1 = *(const float4*)(f_gam + o0 + 4);
    fv[0]=f0.x; fv[1]=f0.y; fv[2]=f0.z; fv[3]=f0.w; fv[4]=f1.x; fv[5]=f1.y; fv[6]=f1.z; fv[7]=f1.w;
    float4 d0 = *(const float4*)(dt_bias + c0); float4 d1 = *(const float4*)(dt_bias + c0 + 4);
    db[0]=d0.x; db[1]=d0.y; db[2]=d0.z; db[3]=d0.w; db[4]=d1.x; db[5]=d1.y; db[6]=d1.z; db[7]=d1.w; }
  float og[8];
#pragma unroll
  for (int j = 0; j < 8; j++) {
    float f = fv[j] + db[j];
    float sp = (f > 20.f) ? f : log1pf(expf(f));
    og[j] = -a_h * sp;                       // g (log-decay), exp applied in scan
  }
  *(float4*)(f_gam + o0)     = make_float4(og[0], og[1], og[2], og[3]);
  *(float4*)(f_gam + o0 + 4) = make_float4(og[4], og[5], og[6], og[7]);
  if (tid < NH) {
    float b = beta_io[(size_t)t * NH + tid];
    beta_io[(size_t)t * NH + tid] = 1.f / (1.f + expf(-b));
  }
}

// ---------------- chunked WY delta-rule scan (C=16, MFMA) ----------------
// 128 blocks = (head, v-tile of 16 cols); 64 threads = 1 wave.
// Per chunk: cumg = cumsum(g) per channel; mid-shift c=cumg[t=7] bounds all
// exponents by e^±~80 (fp32/bf16-safe). khat=k*e^(cumg-c), ktil=k*e^(c-cumg),
// khs=k*e^cumg, similarly qhat/qhs. W^T = mfma(ktil,khat); M = tril(mfma(qhat,
// ktil)); P^T = mfma(S0^T, khs); 16-step fwd substitution for DV (bpermute
// broadcasts, upper-tri garbage lands in dead lanes); O^T = mfma(S0^T,qhs) +
// mfma(DV^T, M^T); S' = e2*(mfma(DV^T, Ktil) + e^c * S0). Exact same math as
// the sequential recurrence (unrolled within chunk), 256 serial chunk-steps
// instead of 4096 token-steps.
constexpr int CHUNK = 16;
constexpr int NCH = T_TOK / CHUNK;

template<int IMM>
__device__ __forceinline__ float swzf(float x) {
  return __builtin_bit_cast(float, __builtin_amdgcn_ds_swizzle(__builtin_bit_cast(int, x), IMM));
}
template<int CTRL>
__device__ __forceinline__ float dppadd(float x) {
  int v = __builtin_amdgcn_update_dpp(0, __builtin_bit_cast(int, x), CTRL, 0xF, 0xF, true);
  return x + __builtin_bit_cast(float, v);
}
__device__ __forceinline__ float cumsum16(float x) {  // inclusive scan within 16-lane row
  x = dppadd<0x111>(x);  // row_shr:1
  x = dppadd<0x112>(x);  // row_shr:2
  x = dppadd<0x114>(x);  // row_shr:4
  x = dppadd<0x118>(x);  // row_shr:8
  return x;
}
__device__ __forceinline__ float bperm(int lane, float x) {
  return __builtin_bit_cast(float, __builtin_amdgcn_ds_bpermute(lane << 2, __builtin_bit_cast(int, x)));
}
__device__ __forceinline__ floatx2 bfpair(unsigned u) {
  floatx2 r;
  r[0] = __builtin_bit_cast(float, u << 16);
  r[1] = __builtin_bit_cast(float, u & 0xFFFF0000u);
  return r;
}

__global__ __launch_bounds__(64, 1) void scan_wy(
    const bf16_t* __restrict__ qn, const bf16_t* __restrict__ kn,
    const bf16_t* __restrict__ vn, const float* __restrict__ gg,
    const float* __restrict__ beta, float* __restrict__ o) {
  const int h  = blockIdx.x >> 3;   // 16 heads
  const int vt = blockIdx.x & 7;    // 8 v-tiles of 16
  const int l  = threadIdx.x;
  const int tl = l & 15;            // t within chunk (A-frag row / C col)
  const int gr = l >> 4;            // lane group 0..3

  __shared__ bf16_t KldsT[128][18];   // ktil transposed [k][t], row pad 18 (bank spread)
  __shared__ float  SldsT[16][132];   // S^T [v][k], row pad 132
  __shared__ float  Mlds[16][20];     // masked M [t][j], row pad 20
  __shared__ float  DVlds[16][16];    // dv [t][v]
  __shared__ float  eclds[128];       // exp(c) per k
  __shared__ float  e2lds[128];       // exp(cumg15 - c) per k

  for (int i = l; i < 16 * 132; i += 64) (&SldsT[0][0])[i] = 0.f;

  float S[8][4];                      // S^T C-layout: k = kt*16+tl, v = 4*gr+ri
#pragma unroll
  for (int kt = 0; kt < 8; kt++)
#pragma unroll
    for (int ri = 0; ri < 4; ri++) S[kt][ri] = 0.f;

  const int kb0 = h * DH + gr * 8;           // A-layout k base
  const int vb0 = h * DH + vt * 16 + gr * 4; // V/O column base
  constexpr float scale = 0.08838834764831845f;

  for (int c = 0; c < NCH; ++c) {
    const size_t rowoff = (size_t)(c * CHUNK + tl) * CH;

    // ---------- A phase (independent of S) ----------
    floatx4 wt = (floatx4){0.f, 0.f, 0.f, 0.f};
    floatx4 m  = (floatx4){0.f, 0.f, 0.f, 0.f};
    bf16x8 khs[4], qhs[4];
#pragma unroll
    for (int kb = 0; kb < 4; kb++) {
      const int ke = kb0 + kb * 32;
      float4 ga = *(const float4*)(gg + rowoff + ke);
      float4 gb = *(const float4*)(gg + rowoff + ke + 4);
      float cm[8] = {ga.x, ga.y, ga.z, ga.w, gb.x, gb.y, gb.z, gb.w};
      float lamh[8], lamt[8], ec[8], e2[8];
#pragma unroll
      for (int j = 0; j < 8; j++) {
        float cs   = cumsum16(cm[j]);                 // inclusive cumg over t
        float cmid = swzf<(7 << 5) | 0x10>(cs);       // c = cumg at t=7
        lamh[j] = __expf(cs - cmid);
        lamt[j] = __expf(cmid - cs);
        ec[j]   = __expf(cmid);
        e2[j]   = swzf<(15 << 5) | 0x10>(lamh[j]);    // exp(cumg15 - c)
      }
      if (tl == 0) {
#pragma unroll
        for (int j = 0; j < 8; j++) {
          eclds[kb * 32 + gr * 8 + j] = ec[j];
          e2lds[kb * 32 + gr * 8 + j] = e2[j];
        }
      }
      uint4 kr = *(const uint4*)(kn + rowoff + ke);
      uint4 qr = *(const uint4*)(qn + rowoff + ke);
      float kf[8], qf[8];
      { floatx2 a0 = bfpair(kr.x), a1 = bfpair(kr.y), a2 = bfpair(kr.z), a3 = bfpair(kr.w);
        kf[0]=a0[0];kf[1]=a0[1];kf[2]=a1[0];kf[3]=a1[1];kf[4]=a2[0];kf[5]=a2[1];kf[6]=a3[0];kf[7]=a3[1];
        floatx2 b0 = bfpair(qr.x), b1 = bfpair(qr.y), b2 = bfpair(qr.z), b3 = bfpair(qr.w);
        qf[0]=b0[0];qf[1]=b0[1];qf[2]=b1[0];qf[3]=b1[1];qf[4]=b2[0];qf[5]=b2[1];qf[6]=b3[0];qf[7]=b3[1]; }
      bf16x8 khat, ktil, qhat;
#pragma unroll
      for (int j = 0; j < 8; j++) {
        khat[j] = (bf16_t)(kf[j] * lamh[j]);
        ktil[j] = (bf16_t)(kf[j] * lamt[j]);
        qhat[j] = (bf16_t)(qf[j] * lamh[j]);
        khs[kb][j] = (bf16_t)(kf[j] * lamh[j] * ec[j]);   // k * exp(cumg)
        qhs[kb][j] = (bf16_t)(qf[j] * lamh[j] * ec[j]);
      }
      wt = __builtin_amdgcn_mfma_f32_16x16x32_bf16(ktil, khat, wt, 0, 0, 0);  // W^T
      m  = __builtin_amdgcn_mfma_f32_16x16x32_bf16(qhat, ktil, m,  0, 0, 0);  // M
#pragma unroll
      for (int j = 0; j < 8; j++) KldsT[kb * 32 + gr * 8 + j][tl] = ktil[j];
    }
    // mask M (keep t >= j) and stash
#pragma unroll
    for (int ri = 0; ri < 4; ri++)
      Mlds[4 * gr + ri][tl] = (4 * gr + ri >= tl) ? m[ri] : 0.f;
    // W columns for the solve: wcol[t] = W[tl][t]
    float wcol[16];
#pragma unroll
    for (int t = 0; t < 16; t++) wcol[t] = bperm(((t >> 2) << 4) | tl, wt[t & 3]);
    // beta, V  (row t = tl; v-cols 4*gr..+3)
    const float bmy = beta[(size_t)(c * CHUNK + tl) * NH + h];
    float vv[4];
    { uint2 vr = *(const uint2*)(vn + rowoff + vb0);
      floatx2 v01 = bfpair(vr.x), v23 = bfpair(vr.y);
      vv[0] = v01[0]; vv[1] = v01[1]; vv[2] = v23[0]; vv[3] = v23[1]; }

    // ---------- B phase (depends on S0) ----------
    floatx4 p  = (floatx4){0.f, 0.f, 0.f, 0.f};
    floatx4 o1 = (floatx4){0.f, 0.f, 0.f, 0.f};
#pragma unroll
    for (int kb = 0; kb < 4; kb++) {
      float4 sa = *(const float4*)(&SldsT[tl][kb * 32 + gr * 8]);
      float4 sb = *(const float4*)(&SldsT[tl][kb * 32 + gr * 8 + 4]);
      bf16x8 s0a;
      s0a[0]=(bf16_t)sa.x; s0a[1]=(bf16_t)sa.y; s0a[2]=(bf16_t)sa.z; s0a[3]=(bf16_t)sa.w;
      s0a[4]=(bf16_t)sb.x; s0a[5]=(bf16_t)sb.y; s0a[6]=(bf16_t)sb.z; s0a[7]=(bf16_t)sb.w;
      p  = __builtin_amdgcn_mfma_f32_16x16x32_bf16(s0a, khs[kb], p,  0, 0, 0);  // (K^S S0)^T
      o1 = __builtin_amdgcn_mfma_f32_16x16x32_bf16(s0a, qhs[kb], o1, 0, 0, 0);  // (Q^S S0)^T
    }
    float acc[4], dvs[4] = {0.f, 0.f, 0.f, 0.f};
#pragma unroll
    for (int ri = 0; ri < 4; ri++) acc[ri] = vv[ri] - p[ri];
    // forward substitution: dv_t = b_t*(acc_t); acc_{t'} -= W[t',t]*dv_t
#pragma unroll
    for (int t = 0; t < 16; t++) {
      float cand[4], dvb[4];
#pragma unroll
      for (int ri = 0; ri < 4; ri++) cand[ri] = bmy * acc[ri];
#pragma unroll
      for (int ri = 0; ri < 4; ri++) dvb[ri] = bperm((gr << 4) | t, cand[ri]);
      const bool own = (tl == t);
#pragma unroll
      for (int ri = 0; ri < 4; ri++) dvs[ri] = own ? cand[ri] : dvs[ri];
#pragma unroll
      for (int ri = 0; ri < 4; ri++) acc[ri] = fmaf(-wcol[t], dvb[ri], acc[ri]);
    }
    *(float4*)(&DVlds[tl][4 * gr]) = make_float4(dvs[0], dvs[1], dvs[2], dvs[3]);
    // DV^T A-frag: row v = tl, t-elems gr*8+jj (groups 0,1; 2,3 zero-pad)
    bf16x8 dva = {};
    if (gr < 2) {
#pragma unroll
      for (int jj = 0; jj < 8; jj++) dva[jj] = (bf16_t)DVlds[gr * 8 + jj][tl];
    }
    // M^T B-frag: col t = tl, j-elems gr*8+jj
    bf16x8 mfr = {};
    if (gr < 2) {
      float4 ma = *(const float4*)(&Mlds[tl][gr * 8]);
      float4 mb = *(const float4*)(&Mlds[tl][gr * 8 + 4]);
      mfr[0]=(bf16_t)ma.x; mfr[1]=(bf16_t)ma.y; mfr[2]=(bf16_t)ma.z; mfr[3]=(bf16_t)ma.w;
      mfr[4]=(bf16_t)mb.x; mfr[5]=(bf16_t)mb.y; mfr[6]=(bf16_t)mb.z; mfr[7]=(bf16_t)mb.w;
    }
    floatx4 o2 = __builtin_amdgcn_mfma_f32_16x16x32_bf16(
        dva, mfr, (floatx4){0.f, 0.f, 0.f, 0.f}, 0, 0, 0);
    { float4 ov = make_float4((o1[0] + o2[0]) * scale, (o1[1] + o2[1]) * scale,
                              (o1[2] + o2[2]) * scale, (o1[3] + o2[3]) * scale);
      *(float4*)(o + rowoff + vb0) = ov; }
    // S update: S' = e2 * (DV^T Ktil + exp(c)*S0)
#pragma unroll
    for (int kt = 0; kt < 8; kt++) {
      bf16x8 ktb = {};
      if (gr < 2) {
        const unsigned* rp = (const unsigned*)&KldsT[kt * 16 + tl][gr * 8];
        uintx4 u = {rp[0], rp[1], rp[2], rp[3]};
        ktb = __builtin_bit_cast(bf16x8, u);
      }
      const float ecK = eclds[kt * 16 + tl];
      const float e2K = e2lds[kt * 16 + tl];
      floatx4 sa;
#pragma unroll
      for (int ri = 0; ri < 4; ri++) sa[ri] = ecK * S[kt][ri];
      sa = __builtin_amdgcn_mfma_f32_16x16x32_bf16(dva, ktb, sa, 0, 0, 0);
#pragma unroll
      for (int ri = 0; ri < 4; ri++) S[kt][ri] = e2K * sa[ri];
    }
    // publish S^T for next chunk's A-frag reads
#pragma unroll
    for (int kt = 0; kt < 8; kt++)
#pragma unroll
      for (int ri = 0; ri < 4; ri++)
        SldsT[4 * gr + ri][kt * 16 + tl] = S[kt][ri];
  }
}

// ---------------- postprocess: RMSNorm * norm_w * silu(gate bf16) -> bf16 ----------------
__global__ __launch_bounds__(256) void postprocess(
    const float* __restrict__ o, const bf16_t* __restrict__ gate,
    const float* __restrict__ norm_w, bf16_t* __restrict__ og) {
  const int t = blockIdx.x, tid = threadIdx.x;
  const int c0 = tid * 8, d0 = c0 & 127;
  const size_t o0 = (size_t)t * CH + c0;
  float ov[8], gv[8], nw[8];
  { float4 a = *(const float4*)(o + o0);    float4 b = *(const float4*)(o + o0 + 4);
    ov[0]=a.x; ov[1]=a.y; ov[2]=a.z; ov[3]=a.w; ov[4]=b.x; ov[5]=b.y; ov[6]=b.z; ov[7]=b.w;
    bf16x8 g8 = *(const bf16x8*)(gate + o0);
    for (int j = 0; j < 8; j++) gv[j] = (float)g8[j];
    float4 e = *(const float4*)(norm_w + d0); float4 f = *(const float4*)(norm_w + d0 + 4);
    nw[0]=e.x; nw[1]=e.y; nw[2]=e.z; nw[3]=e.w; nw[4]=f.x; nw[5]=f.y; nw[6]=f.z; nw[7]=f.w; }
  float ss = 0.f;
#pragma unroll
  for (int j = 0; j < 8; j++) ss += ov[j] * ov[j];
#pragma unroll
  for (int m = 1; m < 16; m <<= 1) ss += __shfl_xor(ss, m);
  const float rs = rsqrtf(ss * (1.f / 128.f) + 1e-6f);
  bf16x8 r;
#pragma unroll
  for (int j = 0; j < 8; j++) {
    float g = gv[j];
    float val = ov[j] * rs * nw[j] * (g / (1.f + expf(-g)));
    r[j] = (bf16_t)val;
  }
  *(bf16x8*)(og + o0) = r;
}

// ---------------- host launcher ----------------
static inline void launch_gemm(const bf16_t* A, int lda, const bf16_t* Bt, int ldb,
                               void* C, int ldc, int M, int N, int K, bool obf16,
                               hipStream_t s) {
  dim3 grid(M / 128, (N + 127) / 128);
  if (obf16) gemm_bf16<true><<<grid, 256, 0, s>>>(A, lda, Bt, ldb, C, ldc, M, N, K);
  else       gemm_bf16<false><<<grid, 256, 0, s>>>(A, lda, Bt, ldb, C, ldc, M, N, K);
}

extern "C" void kernel_launch(void* const* d_in, const int* in_sizes, int n_in,
                              void* d_out, int out_size, void* d_ws, size_t ws_size,
                              hipStream_t stream) {
  const float* x       = (const float*)d_in[0];
  const float* Wq      = (const float*)d_in[1];
  const float* Wk      = (const float*)d_in[2];
  const float* Wv      = (const float*)d_in[3];
  const float* wqc     = (const float*)d_in[4];
  const float* wkc     = (const float*)d_in[5];
  const float* wvc     = (const float*)d_in[6];
  const float* A_log   = (const float*)d_in[7];
  const float* dt_bias = (const float*)d_in[8];
  const float* Wfa     = (const float*)d_in[9];
  const float* Wfb     = (const float*)d_in[10];
  const float* Wb      = (const float*)d_in[11];
  const float* Wga     = (const float*)d_in[12];
  const float* Wgb     = (const float*)d_in[13];
  const float* norm_w  = (const float*)d_in[14];
  const float* Wo      = (const float*)d_in[15];

  char* w = (char*)d_ws;
  size_t off = 0;
  auto give = [&](size_t bytes) -> void* {
    size_t cur = off;
    off = (off + bytes + 255) & ~(size_t)255;
    return (void*)(w + cur);
  };
  bf16_t* Wbig = (bf16_t*)give((size_t)CH * HID * 2);   // reused: WqT,WkT,WvT,WoT
  bf16_t* WfaT = (bf16_t*)give((size_t)128 * HID * 2);
  bf16_t* WgaT = (bf16_t*)give((size_t)128 * HID * 2);
  bf16_t* WfbT = (bf16_t*)give((size_t)CH * 128 * 2);
  bf16_t* WgbT = (bf16_t*)give((size_t)CH * 128 * 2);
  bf16_t* WbT  = (bf16_t*)give((size_t)NH * HID * 2);
  bf16_t* Ax   = (bf16_t*)give((size_t)T_TOK * HID * 2);  // 16 MiB
  bf16_t* raw0 = (bf16_t*)give((size_t)T_TOK * CH * 2);   // 16 MiB, reused q/k/v raw
  bf16_t* qnb  = (bf16_t*)give((size_t)T_TOK * CH * 2);
  bf16_t* knb  = (bf16_t*)give((size_t)T_TOK * CH * 2);
  bf16_t* vnb  = (bf16_t*)give((size_t)T_TOK * CH * 2);
  bf16_t* f1b  = (bf16_t*)give((size_t)T_TOK * 128 * 2);
  bf16_t* g1b  = (bf16_t*)give((size_t)T_TOK * 128 * 2);
  float*  fbuf = (float*)give((size_t)T_TOK * CH * 4);    // f_pre -> g (log decay) in-place
  bf16_t* gateb= (bf16_t*)give((size_t)T_TOK * CH * 2);
  float*  betab= (float*)give((size_t)T_TOK * NH * 4);
  // aliases over dead regions:
  float*  obuf = (float*)Ax;    // 32 MiB = Ax(16)+raw0(16), both dead before scan
  bf16_t* ogb  = qnb;           // qnb dead after scan

  auto tr = [&](const float* in, bf16_t* out, int R, int C) {
    transpose_cast<<<dim3((R + 31) / 32, (C + 31) / 32), 256, 0, stream>>>(in, out, R, C);
  };

  // 1) cast x, small weight transposes
  cast_to_bf16<<<dim3((T_TOK * HID) / 2048), 256, 0, stream>>>(x, Ax, T_TOK * HID);
  tr(Wfa, WfaT, HID, 128); tr(Wga, WgaT, HID, 128);
  tr(Wfb, WfbT, 128, CH);  tr(Wgb, WgbT, 128, CH);
  tr(Wb, WbT, HID, NH);

  // 2) q/k/v: transpose weight -> GEMM -> conv+silu(+l2norm), reusing Wbig and raw0
  tr(Wq, Wbig, HID, CH);
  launch_gemm(Ax, HID, Wbig, HID, raw0, CH, T_TOK, CH, HID, true, stream);
  conv_silu<true><<<dim3(T_TOK), 256, 0, stream>>>(raw0, wqc, qnb);
  tr(Wk, Wbig, HID, CH);
  launch_gemm(Ax, HID, Wbig, HID, raw0, CH, T_TOK, CH, HID, true, stream);
  conv_silu<true><<<dim3(T_TOK), 256, 0, stream>>>(raw0, wkc, knb);
  tr(Wv, Wbig, HID, CH);
  launch_gemm(Ax, HID, Wbig, HID, raw0, CH, T_TOK, CH, HID, true, stream);
  conv_silu<false><<<dim3(T_TOK), 256, 0, stream>>>(raw0, wvc, vnb);

  // 3) f/g/beta chains
  launch_gemm(Ax, HID, WfaT, HID, f1b, 128, T_TOK, 128, HID, true, stream);
  launch_gemm(Ax, HID, WgaT, HID, g1b, 128, T_TOK, 128, HID, true, stream);
  launch_gemm(Ax, HID, WbT, HID, betab, NH, T_TOK, NH, HID, false, stream);
  launch_gemm(f1b, 128, WfbT, 128, fbuf, CH, T_TOK, CH, 128, false, stream);
  launch_gemm(g1b, 128, WgbT, 128, gateb, CH, T_TOK, CH, 128, true, stream);
  gamma_beta<<<dim3(T_TOK), 256, 0, stream>>>(fbuf, dt_bias, A_log, betab);

  // 4) chunked WY delta-rule scan: 128 blocks (16 heads x 8 v-tiles) x 64 threads
  scan_wy<<<dim3(128), 64, 0, stream>>>(qnb, knb, vnb, fbuf, betab, obuf);

  // 5) gated RMSNorm -> bf16 (ogb aliases qnb)
  postprocess<<<dim3(T_TOK), 256, 0, stream>>>(obuf, gateb, norm_w, ogb);

  // 6) output projection
  tr(Wo, Wbig, CH, HID);
  launch_gemm(ogb, CH, Wbig, CH, (float*)d_out, HID, T_TOK, HID, CH, false, stream);
}

// Round 8
// 1125.484 us; speedup vs baseline: 1.7994x; 1.7994x over previous
//
#include <hip/hip_runtime.h>
#include <hip/hip_bf16.h>
#include <math.h>

typedef __bf16 bf16_t;
typedef __bf16 bf16x8 __attribute__((ext_vector_type(8)));
typedef float  floatx4 __attribute__((ext_vector_type(4)));
typedef float  floatx2 __attribute__((ext_vector_type(2)));
typedef unsigned uintx4 __attribute__((ext_vector_type(4)));

constexpr int T_TOK = 4096;
constexpr int HID   = 2048;
constexpr int NH    = 16;
constexpr int DH    = 128;   // head dim
constexpr int CH    = 2048;  // NH*DH
constexpr int CHUNK = 16;
constexpr int NCH   = T_TOK / CHUNK;   // 256

// ---------------- cast fp32 -> bf16 (row-major preserved) ----------------
__global__ __launch_bounds__(256) void cast_to_bf16(const float* __restrict__ in,
                                                    bf16_t* __restrict__ out, int n) {
  int i = (blockIdx.x * 256 + threadIdx.x) * 8;
  if (i >= n) return;
  float4 a = *(const float4*)(in + i);
  float4 b = *(const float4*)(in + i + 4);
  bf16x8 o;
  o[0]=(bf16_t)a.x; o[1]=(bf16_t)a.y; o[2]=(bf16_t)a.z; o[3]=(bf16_t)a.w;
  o[4]=(bf16_t)b.x; o[5]=(bf16_t)b.y; o[6]=(bf16_t)b.z; o[7]=(bf16_t)b.w;
  *(bf16x8*)(out + i) = o;
}

// ---------------- transpose + cast: in fp32 [R,C] -> out bf16 [C,R] ----------------
__global__ __launch_bounds__(256) void transpose_cast(const float* __restrict__ in,
                                                      bf16_t* __restrict__ out, int R, int C) {
  __shared__ float tile[32][33];
  int tx = threadIdx.x & 31;
  int ty = threadIdx.x >> 5;  // 0..7
  int r0 = blockIdx.x * 32;
  int c0 = blockIdx.y * 32;
#pragma unroll
  for (int i = 0; i < 4; i++) {
    int r = ty + i * 8;
    float v = 0.f;
    if (r0 + r < R && c0 + tx < C) v = in[(size_t)(r0 + r) * C + (c0 + tx)];
    tile[r][tx] = v;
  }
  __syncthreads();
#pragma unroll
  for (int i = 0; i < 4; i++) {
    int cr = ty + i * 8;
    if (c0 + cr < C && r0 + tx < R)
      out[(size_t)(c0 + cr) * R + (r0 + tx)] = (bf16_t)tile[tx][cr];
  }
}

// ---------------- bf16 MFMA GEMM: C[M,N] = A[M,K] * Bt[N,K]^T ----------------
template<bool OUT_BF16>
__global__ __launch_bounds__(256) void gemm_bf16(
    const bf16_t* __restrict__ A, int lda,
    const bf16_t* __restrict__ Bt, int ldb,
    void* __restrict__ Cv, int ldc, int M, int N, int K) {
  __shared__ bf16_t sA[128][40];
  __shared__ bf16_t sB[128][40];
  const int tid  = threadIdx.x;
  const int bm0  = blockIdx.x * 128;
  const int bn0  = blockIdx.y * 128;
  const int wave = tid >> 6;
  const int lane = tid & 63;
  const int wm   = (wave & 1) * 64;
  const int wn   = (wave >> 1) * 64;
  const int fm   = lane & 15;
  const int kq   = lane >> 4;

  floatx4 acc[4][4];
#pragma unroll
  for (int mi = 0; mi < 4; mi++)
#pragma unroll
    for (int ni = 0; ni < 4; ni++)
      acc[mi][ni] = (floatx4){0.f, 0.f, 0.f, 0.f};

  const int sr = tid >> 2;
  const int sk = (tid & 3) * 8;
  const bool bval0 = (bn0 + sr) < N;
  const bool bval1 = (bn0 + sr + 64) < N;
  const bf16_t* Ag0 = A + (size_t)(bm0 + sr) * lda + sk;
  const bf16_t* Ag1 = Ag0 + (size_t)64 * lda;
  const bf16_t* Bg0 = Bt + (size_t)(bn0 + sr) * ldb + sk;
  const bf16_t* Bg1 = Bg0 + (size_t)64 * ldb;

  for (int k0 = 0; k0 < K; k0 += 32) {
    float4 a0 = *(const float4*)(Ag0 + k0);
    float4 a1 = *(const float4*)(Ag1 + k0);
    float4 b0 = bval0 ? *(const float4*)(Bg0 + k0) : make_float4(0.f, 0.f, 0.f, 0.f);
    float4 b1 = bval1 ? *(const float4*)(Bg1 + k0) : make_float4(0.f, 0.f, 0.f, 0.f);
    __syncthreads();
    *(float4*)(&sA[sr][sk])      = a0;
    *(float4*)(&sA[sr + 64][sk]) = a1;
    *(float4*)(&sB[sr][sk])      = b0;
    *(float4*)(&sB[sr + 64][sk]) = b1;
    __syncthreads();
    bf16x8 afr[4], bfr[4];
#pragma unroll
    for (int i = 0; i < 4; i++) {
      afr[i] = *(const bf16x8*)(&sA[wm + i * 16 + fm][kq * 8]);
      bfr[i] = *(const bf16x8*)(&sB[wn + i * 16 + fm][kq * 8]);
    }
#pragma unroll
    for (int mi = 0; mi < 4; mi++)
#pragma unroll
      for (int ni = 0; ni < 4; ni++)
        acc[mi][ni] = __builtin_amdgcn_mfma_f32_16x16x32_bf16(afr[mi], bfr[ni], acc[mi][ni], 0, 0, 0);
  }

  const int rr = (lane >> 4) * 4;
#pragma unroll
  for (int mi = 0; mi < 4; mi++) {
#pragma unroll
    for (int r = 0; r < 4; r++) {
      const int row = bm0 + wm + mi * 16 + rr + r;
#pragma unroll
      for (int ni = 0; ni < 4; ni++) {
        const int col = bn0 + wn + ni * 16 + fm;
        if (col < N) {
          if constexpr (OUT_BF16)
            ((bf16_t*)Cv)[(size_t)row * ldc + col] = (bf16_t)acc[mi][ni][r];
          else
            ((float*)Cv)[(size_t)row * ldc + col] = acc[mi][ni][r];
        }
      }
    }
  }
}

// ---------------- conv + silu (+ l2norm) : raw bf16 [T,CH] -> out bf16 [T,CH] ----------------
template<bool L2NORM>
__global__ __launch_bounds__(256) void conv_silu(
    const bf16_t* __restrict__ raw, const float* __restrict__ wconv,
    bf16_t* __restrict__ out) {
  const int t   = blockIdx.x;
  const int tid = threadIdx.x;
  const int c0  = tid * 8;

  float w[8][4];
#pragma unroll
  for (int j = 0; j < 8; j++) {
    float4 t0 = *(const float4*)(wconv + (size_t)(c0 + j) * 4);
    w[j][0] = t0.x; w[j][1] = t0.y; w[j][2] = t0.z; w[j][3] = t0.w;
  }
  float a[8] = {};
#pragma unroll
  for (int i = 0; i < 4; i++) {
    int tr = t - 3 + i;
    if (tr < 0) continue;
    bf16x8 xr = *(const bf16x8*)(raw + (size_t)tr * CH + c0);
#pragma unroll
    for (int j = 0; j < 8; j++) a[j] += w[j][i] * (float)xr[j];
  }
  float s = 0.f;
#pragma unroll
  for (int j = 0; j < 8; j++) {
    a[j] = a[j] / (1.f + expf(-a[j]));  // silu
    s += a[j] * a[j];
  }
  float rs = 1.f;
  if constexpr (L2NORM) {
#pragma unroll
    for (int m = 1; m < 16; m <<= 1) s += __shfl_xor(s, m);
    rs = rsqrtf(s + 1e-6f);
  }
  bf16x8 r;
#pragma unroll
  for (int j = 0; j < 8; j++) r[j] = (bf16_t)(a[j] * rs);
  *(bf16x8*)(out + (size_t)t * CH + c0) = r;
}

// ---------------- gamma: writes g = -a*softplus (LOG decay) + beta sigmoid ----------------
__global__ __launch_bounds__(256) void gamma_beta(
    float* __restrict__ f_gam, const float* __restrict__ dt_bias,
    const float* __restrict__ A_log, float* __restrict__ beta_io) {
  const int t   = blockIdx.x;
  const int tid = threadIdx.x;
  const int c0  = tid * 8;
  const int h   = c0 >> 7;
  const float a_h = expf(A_log[h]);
  const size_t o0 = (size_t)t * CH + c0;
  float fv[8], db[8];
  { float4 f0 = *(const float4*)(f_gam + o0);   float4 f1 = *(const float4*)(f_gam + o0 + 4);
    fv[0]=f0.x; fv[1]=f0.y; fv[2]=f0.z; fv[3]=f0.w; fv[4]=f1.x; fv[5]=f1.y; fv[6]=f1.z; fv[7]=f1.w;
    float4 d0 = *(const float4*)(dt_bias + c0); float4 d1 = *(const float4*)(dt_bias + c0 + 4);
    db[0]=d0.x; db[1]=d0.y; db[2]=d0.z; db[3]=d0.w; db[4]=d1.x; db[5]=d1.y; db[6]=d1.z; db[7]=d1.w; }
  float og[8];
#pragma unroll
  for (int j = 0; j < 8; j++) {
    float f = fv[j] + db[j];
    float sp = (f > 20.f) ? f : log1pf(expf(f));
    og[j] = -a_h * sp;                       // g (log-decay), exp applied in prep
  }
  *(float4*)(f_gam + o0)     = make_float4(og[0], og[1], og[2], og[3]);
  *(float4*)(f_gam + o0 + 4) = make_float4(og[4], og[5], og[6], og[7]);
  if (tid < NH) {
    float b = beta_io[(size_t)t * NH + tid];
    beta_io[(size_t)t * NH + tid] = 1.f / (1.f + expf(-b));
  }
}

// ---------------- helpers for WY kernels ----------------
template<int IMM>
__device__ __forceinline__ float swzf(float x) {
  return __builtin_bit_cast(float, __builtin_amdgcn_ds_swizzle(__builtin_bit_cast(int, x), IMM));
}
template<int CTRL>
__device__ __forceinline__ float dppadd(float x) {
  int v = __builtin_amdgcn_update_dpp(0, __builtin_bit_cast(int, x), CTRL, 0xF, 0xF, true);
  return x + __builtin_bit_cast(float, v);
}
__device__ __forceinline__ float cumsum16(float x) {  // inclusive scan within 16-lane row
  x = dppadd<0x111>(x);  // row_shr:1
  x = dppadd<0x112>(x);  // row_shr:2
  x = dppadd<0x114>(x);  // row_shr:4
  x = dppadd<0x118>(x);  // row_shr:8
  return x;
}
__device__ __forceinline__ float bperm(int lane, float x) {
  return __builtin_bit_cast(float, __builtin_amdgcn_ds_bpermute(lane << 2, __builtin_bit_cast(int, x)));
}
__device__ __forceinline__ floatx2 bfpair(unsigned u) {
  floatx2 r;
  r[0] = __builtin_bit_cast(float, u << 16);
  r[1] = __builtin_bit_cast(float, u & 0xFFFF0000u);
  return r;
}

// ---------------- WY prep: fully parallel over (head, chunk) ----------------
// Per (h,c): cumg/exp factors; khs=k*e^cumg / qhs=q*e^cumg written IN PLACE over
// kn/qn (same (t,k) slice, block-disjoint); ktil frag-transposed to ktilT;
// W=K~K^T and M=tril(Q^ K~^T) via MFMA; T = inv(I+trilس(diag(b)W))*diag(b) in
// exact f32 forward substitution; masked-M stored as ready B-frag; ec/e2 per k.
// Moves ALL chunk-local VALU (cumsum chains, ~96 expf, packing, solve prep) off
// the serial kernel's critical path. Verified math identical to round-7 kernel.
__global__ __launch_bounds__(64) void wy_prep(
    bf16_t* __restrict__ qn, bf16_t* __restrict__ kn,
    const float* __restrict__ gg, const float* __restrict__ beta,
    bf16_t* __restrict__ ktilT, float* __restrict__ Tm,
    bf16_t* __restrict__ MBf, float* __restrict__ ecT, float* __restrict__ e2T) {
  const int hc = blockIdx.x;        // h*NCH + c
  const int h  = hc >> 8;           // NCH = 256
  const int c  = hc & 255;
  const int l  = threadIdx.x;
  const int tl = l & 15;            // t within chunk
  const int gr = l >> 4;            // 0..3

  __shared__ bf16_t KldsT[128][24];  // ktil^T [k][t], 48B rows (16B-aligned)
  __shared__ float  Wlds[16][17];    // W[t][s]
  __shared__ float  Mlds[16][17];    // masked M[t][s]
  __shared__ float  eclds[128], e2lds[128];
  __shared__ float  blds[16];

  const int kb0 = h * DH + gr * 8;
  const size_t rowoff = (size_t)(c * CHUNK + tl) * CH;

  if (gr == 0) blds[tl] = beta[(size_t)(c * CHUNK + tl) * NH + h];

  floatx4 wt = (floatx4){0.f, 0.f, 0.f, 0.f};
  floatx4 m  = (floatx4){0.f, 0.f, 0.f, 0.f};
  bf16x8 khs[4], qhs[4];
#pragma unroll
  for (int kb = 0; kb < 4; kb++) {
    const int ke = kb0 + kb * 32;
    float4 ga = *(const float4*)(gg + rowoff + ke);
    float4 gb = *(const float4*)(gg + rowoff + ke + 4);
    float cm[8] = {ga.x, ga.y, ga.z, ga.w, gb.x, gb.y, gb.z, gb.w};
    float lamh[8], lamt[8], ec[8], e2[8];
#pragma unroll
    for (int j = 0; j < 8; j++) {
      float cs   = cumsum16(cm[j]);                 // inclusive cumg over t
      float cmid = swzf<(7 << 5) | 0x10>(cs);       // c = cumg at t=7
      lamh[j] = __expf(cs - cmid);
      lamt[j] = __expf(cmid - cs);
      ec[j]   = __expf(cmid);
      e2[j]   = swzf<(15 << 5) | 0x10>(lamh[j]);    // exp(cumg15 - c)
    }
    if (tl == 0) {
#pragma unroll
      for (int j = 0; j < 8; j++) {
        eclds[kb * 32 + gr * 8 + j] = ec[j];
        e2lds[kb * 32 + gr * 8 + j] = e2[j];
      }
    }
    uint4 kr = *(const uint4*)(kn + rowoff + ke);
    uint4 qr = *(const uint4*)(qn + rowoff + ke);
    float kf[8], qf[8];
    { floatx2 a0 = bfpair(kr.x), a1 = bfpair(kr.y), a2 = bfpair(kr.z), a3 = bfpair(kr.w);
      kf[0]=a0[0];kf[1]=a0[1];kf[2]=a1[0];kf[3]=a1[1];kf[4]=a2[0];kf[5]=a2[1];kf[6]=a3[0];kf[7]=a3[1];
      floatx2 b0 = bfpair(qr.x), b1 = bfpair(qr.y), b2 = bfpair(qr.z), b3 = bfpair(qr.w);
      qf[0]=b0[0];qf[1]=b0[1];qf[2]=b1[0];qf[3]=b1[1];qf[4]=b2[0];qf[5]=b2[1];qf[6]=b3[0];qf[7]=b3[1]; }
    bf16x8 khat, ktil, qhat;
#pragma unroll
    for (int j = 0; j < 8; j++) {
      khat[j] = (bf16_t)(kf[j] * lamh[j]);
      ktil[j] = (bf16_t)(kf[j] * lamt[j]);
      qhat[j] = (bf16_t)(qf[j] * lamh[j]);
      khs[kb][j] = (bf16_t)(kf[j] * lamh[j] * ec[j]);   // k * exp(cumg)
      qhs[kb][j] = (bf16_t)(qf[j] * lamh[j] * ec[j]);
    }
    wt = __builtin_amdgcn_mfma_f32_16x16x32_bf16(ktil, khat, wt, 0, 0, 0);  // C[s][t]=W[t][s] (col=t,row=s)
    m  = __builtin_amdgcn_mfma_f32_16x16x32_bf16(qhat, ktil, m,  0, 0, 0);  // C[t][s]=M[t][s] (col=s,row=t)
#pragma unroll
    for (int j = 0; j < 8; j++) KldsT[kb * 32 + gr * 8 + j][tl] = ktil[j];
  }
  // in-place khs/qhs stores (all reads of this slice completed above)
#pragma unroll
  for (int kb = 0; kb < 4; kb++) {
    *(uint4*)(kn + rowoff + kb0 + kb * 32) = __builtin_bit_cast(uint4, khs[kb]);
    *(uint4*)(qn + rowoff + kb0 + kb * 32) = __builtin_bit_cast(uint4, qhs[kb]);
  }
  // W, masked M to LDS
#pragma unroll
  for (int ri = 0; ri < 4; ri++) {
    Wlds[tl][4 * gr + ri] = wt[ri];                               // W[t=tl][s=4gr+ri]
    Mlds[4 * gr + ri][tl] = (4 * gr + ri >= tl) ? m[ri] : 0.f;    // M[t][s], tril incl
  }
  // T solve (exact f32): X = inv(I + tril_strict(diag(b)W)); T[t][j] = X[t][j]*b_j
  {
    const int j = tl;
    float x[16];
#pragma unroll
    for (int t = 0; t < 16; t++) {
      float a = 0.f;
#pragma unroll
      for (int s = 0; s < 16; s++)
        if (s < t) a = fmaf(Wlds[t][s], x[s], a);
      x[t] = (t == j) ? 1.f : ((t > j) ? -blds[t] * a : 0.f);
    }
    if (gr == 0) {
      const float bj = blds[j];
#pragma unroll
      for (int t = 0; t < 16; t++)
        Tm[((size_t)hc * 16 + t) * 16 + j] = x[t] * bj;
    }
  }
  // masked-M as ready B-frag (col=t=tl, elems s=gr*8+jj; gr>=2 zero)
  {
    uint4 mbo = {0, 0, 0, 0};
    if (gr < 2) {
      bf16x8 mm;
#pragma unroll
      for (int jj = 0; jj < 8; jj++) mm[jj] = (bf16_t)Mlds[tl][gr * 8 + jj];
      mbo = __builtin_bit_cast(uint4, mm);
    }
    ((uint4*)MBf)[(size_t)hc * 64 + l] = mbo;
  }
  // ktil^T -> global (coalesced rows of 16 bf16)
  for (int i = l; i < 128; i += 64) {
    uint4 a0 = *(const uint4*)&KldsT[i][0];
    uint4 a1 = *(const uint4*)&KldsT[i][8];
    bf16_t* dst = ktilT + ((size_t)hc * 128 + i) * 16;
    *(uint4*)dst = a0;
    *(uint4*)(dst + 8) = a1;
  }
  // ec/e2 transposed for float4 loads: [tl][kt]
  for (int i = l; i < 128; i += 64) {
    ecT[(size_t)hc * 128 + (i & 15) * 8 + (i >> 4)] = eclds[i];
    e2T[(size_t)hc * 128 + (i & 15) * 8 + (i >> 4)] = e2lds[i];
  }
}

// ---------------- serial WY scan: lean B-phase only ----------------
// 128 blocks = (head, v-tile of 16); 64 threads = 1 wave. Per chunk:
// P,O1 = mfma(S0^T, khs/qhs) (8 MFMA); V'=V-P; DV = T*V' via 16 INDEPENDENT
// f32 bperm+FMA (pipelined, not a serial chain; T exact f32 from prep);
// O2 = mfma(DV^T, M^T); S' = e2*(ec*S0 + mfma(DV^T, K~)). All chunk-local
// factors preloaded at iteration top -> latency overlaps the S0/MFMA phase.
__global__ __launch_bounds__(64, 1) void scan_wy2(
    const bf16_t* __restrict__ khsG, const bf16_t* __restrict__ qhsG,
    const bf16_t* __restrict__ vn, const bf16_t* __restrict__ ktilT,
    const float* __restrict__ Tm, const bf16_t* __restrict__ MBf,
    const float* __restrict__ ecT, const float* __restrict__ e2T,
    float* __restrict__ o) {
  const int h  = blockIdx.x >> 3;   // 16 heads
  const int vt = blockIdx.x & 7;    // 8 v-tiles
  const int l  = threadIdx.x;
  const int tl = l & 15;
  const int gr = l >> 4;

  __shared__ float SldsT[16][132];   // S^T [v][k]
  __shared__ float DVlds[16][17];    // dv [t][v]

  for (int i = l; i < 16 * 132; i += 64) (&SldsT[0][0])[i] = 0.f;

  float S[8][4];                     // S^T C-layout: k=kt*16+tl, v=4*gr+ri
#pragma unroll
  for (int kt = 0; kt < 8; kt++)
#pragma unroll
    for (int ri = 0; ri < 4; ri++) S[kt][ri] = 0.f;

  const int kb0 = h * DH + gr * 8;
  const int vb0 = h * DH + vt * 16 + gr * 4;
  const size_t hcBase = (size_t)h * NCH;
  constexpr float scale = 0.08838834764831845f;

  for (int c = 0; c < NCH; ++c) {
    const size_t rowoff = (size_t)(c * CHUNK + tl) * CH;
    const size_t hc = hcBase + c;

    // ---- all global loads up front (S-independent) ----
    uint4 khs[4], qhs[4];
#pragma unroll
    for (int kb = 0; kb < 4; kb++) {
      khs[kb] = *(const uint4*)(khsG + rowoff + kb0 + kb * 32);
      qhs[kb] = *(const uint4*)(qhsG + rowoff + kb0 + kb * 32);
    }
    uint2 vr = *(const uint2*)(vn + rowoff + vb0);
    const float* Trp = Tm + (hc * 16 + tl) * 16;
    floatx4 T0 = *(const floatx4*)(Trp);
    floatx4 T1 = *(const floatx4*)(Trp + 4);
    floatx4 T2 = *(const floatx4*)(Trp + 8);
    floatx4 T3 = *(const floatx4*)(Trp + 12);
    uint4 mb = ((const uint4*)MBf)[hc * 64 + l];
    uint4 ktb[8] = {};
    if (gr < 2) {
#pragma unroll
      for (int kt = 0; kt < 8; kt++)
        ktb[kt] = *(const uint4*)(ktilT + (hc * 128 + kt * 16 + tl) * 16 + gr * 8);
    }
    floatx4 ec0 = *(const floatx4*)(ecT + hc * 128 + tl * 8);
    floatx4 ec1 = *(const floatx4*)(ecT + hc * 128 + tl * 8 + 4);
    floatx4 e20 = *(const floatx4*)(e2T + hc * 128 + tl * 8);
    floatx4 e21 = *(const floatx4*)(e2T + hc * 128 + tl * 8 + 4);

    // ---- P, O1 from S0 (LDS round trip from previous publish) ----
    floatx4 p  = (floatx4){0.f, 0.f, 0.f, 0.f};
    floatx4 o1 = (floatx4){0.f, 0.f, 0.f, 0.f};
#pragma unroll
    for (int kb = 0; kb < 4; kb++) {
      float4 sa = *(const float4*)(&SldsT[tl][kb * 32 + gr * 8]);
      float4 sb = *(const float4*)(&SldsT[tl][kb * 32 + gr * 8 + 4]);
      bf16x8 s0a;
      s0a[0]=(bf16_t)sa.x; s0a[1]=(bf16_t)sa.y; s0a[2]=(bf16_t)sa.z; s0a[3]=(bf16_t)sa.w;
      s0a[4]=(bf16_t)sb.x; s0a[5]=(bf16_t)sb.y; s0a[6]=(bf16_t)sb.z; s0a[7]=(bf16_t)sb.w;
      p  = __builtin_amdgcn_mfma_f32_16x16x32_bf16(s0a, __builtin_bit_cast(bf16x8, khs[kb]), p,  0, 0, 0);
      o1 = __builtin_amdgcn_mfma_f32_16x16x32_bf16(s0a, __builtin_bit_cast(bf16x8, qhs[kb]), o1, 0, 0, 0);
    }
    // ---- V' = V - P ;  DV = T*V' (pipelined bperm, exact f32 T) ----
    float acc[4];
    { floatx2 v01 = bfpair(vr.x), v23 = bfpair(vr.y);
      acc[0] = v01[0] - p[0]; acc[1] = v01[1] - p[1];
      acc[2] = v23[0] - p[2]; acc[3] = v23[1] - p[3]; }
    float dv[4] = {0.f, 0.f, 0.f, 0.f};
#pragma unroll
    for (int s = 0; s < 16; s++) {
      const float ts = (s < 4) ? T0[s] : (s < 8) ? T1[s - 4] : (s < 12) ? T2[s - 8] : T3[s - 12];
#pragma unroll
      for (int ri = 0; ri < 4; ri++)
        dv[ri] = fmaf(ts, bperm((gr << 4) | s, acc[ri]), dv[ri]);
    }
#pragma unroll
    for (int ri = 0; ri < 4; ri++) DVlds[tl][4 * gr + ri] = dv[ri];
    bf16x8 dva = {};
    if (gr < 2) {
#pragma unroll
      for (int jj = 0; jj < 8; jj++) dva[jj] = (bf16_t)DVlds[gr * 8 + jj][tl];
    }
    // ---- O2, store O ----
    floatx4 o2 = __builtin_amdgcn_mfma_f32_16x16x32_bf16(
        dva, __builtin_bit_cast(bf16x8, mb), (floatx4){0.f, 0.f, 0.f, 0.f}, 0, 0, 0);
    { float4 ov = make_float4((o1[0] + o2[0]) * scale, (o1[1] + o2[1]) * scale,
                              (o1[2] + o2[2]) * scale, (o1[3] + o2[3]) * scale);
      *(float4*)(o + rowoff + vb0) = ov; }
    // ---- S update: S' = e2*(ec*S0 + DV^T K~) ----
#pragma unroll
    for (int kt = 0; kt < 8; kt++) {
      const float ecK = (kt < 4) ? ec0[kt] : ec1[kt - 4];
      const float e2K = (kt < 4) ? e20[kt] : e21[kt - 4];
      floatx4 sa;
#pragma unroll
      for (int ri = 0; ri < 4; ri++) sa[ri] = ecK * S[kt][ri];
      sa = __builtin_amdgcn_mfma_f32_16x16x32_bf16(
          dva, __builtin_bit_cast(bf16x8, ktb[kt]), sa, 0, 0, 0);
#pragma unroll
      for (int ri = 0; ri < 4; ri++) S[kt][ri] = e2K * sa[ri];
    }
    // ---- publish S^T for next chunk ----
#pragma unroll
    for (int kt = 0; kt < 8; kt++)
#pragma unroll
      for (int ri = 0; ri < 4; ri++)
        SldsT[4 * gr + ri][kt * 16 + tl] = S[kt][ri];
  }
}

// ---------------- postprocess: RMSNorm * norm_w * silu(gate bf16) -> bf16 ----------------
__global__ __launch_bounds__(256) void postprocess(
    const float* __restrict__ o, const bf16_t* __restrict__ gate,
    const float* __restrict__ norm_w, bf16_t* __restrict__ og) {
  const int t = blockIdx.x, tid = threadIdx.x;
  const int c0 = tid * 8, d0 = c0 & 127;
  const size_t o0 = (size_t)t * CH + c0;
  float ov[8], gv[8], nw[8];
  { float4 a = *(const float4*)(o + o0);    float4 b = *(const float4*)(o + o0 + 4);
    ov[0]=a.x; ov[1]=a.y; ov[2]=a.z; ov[3]=a.w; ov[4]=b.x; ov[5]=b.y; ov[6]=b.z; ov[7]=b.w;
    bf16x8 g8 = *(const bf16x8*)(gate + o0);
    for (int j = 0; j < 8; j++) gv[j] = (float)g8[j];
    float4 e = *(const float4*)(norm_w + d0); float4 f = *(const float4*)(norm_w + d0 + 4);
    nw[0]=e.x; nw[1]=e.y; nw[2]=e.z; nw[3]=e.w; nw[4]=f.x; nw[5]=f.y; nw[6]=f.z; nw[7]=f.w; }
  float ss = 0.f;
#pragma unroll
  for (int j = 0; j < 8; j++) ss += ov[j] * ov[j];
#pragma unroll
  for (int m = 1; m < 16; m <<= 1) ss += __shfl_xor(ss, m);
  const float rs = rsqrtf(ss * (1.f / 128.f) + 1e-6f);
  bf16x8 r;
#pragma unroll
  for (int j = 0; j < 8; j++) {
    float g = gv[j];
    float val = ov[j] * rs * nw[j] * (g / (1.f + expf(-g)));
    r[j] = (bf16_t)val;
  }
  *(bf16x8*)(og + o0) = r;
}

// ---------------- host launcher ----------------
static inline void launch_gemm(const bf16_t* A, int lda, const bf16_t* Bt, int ldb,
                               void* C, int ldc, int M, int N, int K, bool obf16,
                               hipStream_t s) {
  dim3 grid(M / 128, (N + 127) / 128);
  if (obf16) gemm_bf16<true><<<grid, 256, 0, s>>>(A, lda, Bt, ldb, C, ldc, M, N, K);
  else       gemm_bf16<false><<<grid, 256, 0, s>>>(A, lda, Bt, ldb, C, ldc, M, N, K);
}

extern "C" void kernel_launch(void* const* d_in, const int* in_sizes, int n_in,
                              void* d_out, int out_size, void* d_ws, size_t ws_size,
                              hipStream_t stream) {
  const float* x       = (const float*)d_in[0];
  const float* Wq      = (const float*)d_in[1];
  const float* Wk      = (const float*)d_in[2];
  const float* Wv      = (const float*)d_in[3];
  const float* wqc     = (const float*)d_in[4];
  const float* wkc     = (const float*)d_in[5];
  const float* wvc     = (const float*)d_in[6];
  const float* A_log   = (const float*)d_in[7];
  const float* dt_bias = (const float*)d_in[8];
  const float* Wfa     = (const float*)d_in[9];
  const float* Wfb     = (const float*)d_in[10];
  const float* Wb      = (const float*)d_in[11];
  const float* Wga     = (const float*)d_in[12];
  const float* Wgb     = (const float*)d_in[13];
  const float* norm_w  = (const float*)d_in[14];
  const float* Wo      = (const float*)d_in[15];

  char* w = (char*)d_ws;
  size_t off = 0;
  auto give = [&](size_t bytes) -> void* {
    size_t cur = off;
    off = (off + bytes + 255) & ~(size_t)255;
    return (void*)(w + cur);
  };
  bf16_t* Wbig = (bf16_t*)give((size_t)CH * HID * 2);   // reused: WqT,WkT,WvT,WoT
  bf16_t* WfaT = (bf16_t*)give((size_t)128 * HID * 2);
  bf16_t* WgaT = (bf16_t*)give((size_t)128 * HID * 2);
  bf16_t* WfbT = (bf16_t*)give((size_t)CH * 128 * 2);
  bf16_t* WgbT = (bf16_t*)give((size_t)CH * 128 * 2);
  bf16_t* WbT  = (bf16_t*)give((size_t)NH * HID * 2);
  bf16_t* Ax   = (bf16_t*)give((size_t)T_TOK * HID * 2);  // 16 MiB
  bf16_t* raw0 = (bf16_t*)give((size_t)T_TOK * CH * 2);   // 16 MiB, reused q/k/v raw
  bf16_t* qnb  = (bf16_t*)give((size_t)T_TOK * CH * 2);
  bf16_t* knb  = (bf16_t*)give((size_t)T_TOK * CH * 2);
  bf16_t* vnb  = (bf16_t*)give((size_t)T_TOK * CH * 2);
  bf16_t* f1b  = (bf16_t*)give((size_t)T_TOK * 128 * 2);
  bf16_t* g1b  = (bf16_t*)give((size_t)T_TOK * 128 * 2);
  float*  fbuf = (float*)give((size_t)T_TOK * CH * 4);    // f_pre -> g (log decay) in-place
  bf16_t* gateb= (bf16_t*)give((size_t)T_TOK * CH * 2);
  float*  betab= (float*)give((size_t)T_TOK * NH * 4);
  // WY precompute buffers (+28 MiB)
  bf16_t* ktilT= (bf16_t*)give((size_t)NH * NCH * 128 * 16 * 2);  // 16 MiB
  float*  Tmat = (float*)give((size_t)NH * NCH * 256 * 4);        // 4 MiB
  bf16_t* MBf  = (bf16_t*)give((size_t)NH * NCH * 64 * 8 * 2);    // 4 MiB
  float*  ecTb = (float*)give((size_t)NH * NCH * 128 * 4);        // 2 MiB
  float*  e2Tb = (float*)give((size_t)NH * NCH * 128 * 4);        // 2 MiB
  // aliases over dead regions:
  float*  obuf = (float*)Ax;    // 32 MiB = Ax(16)+raw0(16), both dead before scan
  bf16_t* ogb  = qnb;           // qnb dead after scan

  auto tr = [&](const float* in, bf16_t* out, int R, int C) {
    transpose_cast<<<dim3((R + 31) / 32, (C + 31) / 32), 256, 0, stream>>>(in, out, R, C);
  };

  // 1) cast x, small weight transposes
  cast_to_bf16<<<dim3((T_TOK * HID) / 2048), 256, 0, stream>>>(x, Ax, T_TOK * HID);
  tr(Wfa, WfaT, HID, 128); tr(Wga, WgaT, HID, 128);
  tr(Wfb, WfbT, 128, CH);  tr(Wgb, WgbT, 128, CH);
  tr(Wb, WbT, HID, NH);

  // 2) q/k/v: transpose weight -> GEMM -> conv+silu(+l2norm), reusing Wbig and raw0
  tr(Wq, Wbig, HID, CH);
  launch_gemm(Ax, HID, Wbig, HID, raw0, CH, T_TOK, CH, HID, true, stream);
  conv_silu<true><<<dim3(T_TOK), 256, 0, stream>>>(raw0, wqc, qnb);
  tr(Wk, Wbig, HID, CH);
  launch_gemm(Ax, HID, Wbig, HID, raw0, CH, T_TOK, CH, HID, true, stream);
  conv_silu<true><<<dim3(T_TOK), 256, 0, stream>>>(raw0, wkc, knb);
  tr(Wv, Wbig, HID, CH);
  launch_gemm(Ax, HID, Wbig, HID, raw0, CH, T_TOK, CH, HID, true, stream);
  conv_silu<false><<<dim3(T_TOK), 256, 0, stream>>>(raw0, wvc, vnb);

  // 3) f/g/beta chains
  launch_gemm(Ax, HID, WfaT, HID, f1b, 128, T_TOK, 128, HID, true, stream);
  launch_gemm(Ax, HID, WgaT, HID, g1b, 128, T_TOK, 128, HID, true, stream);
  launch_gemm(Ax, HID, WbT, HID, betab, NH, T_TOK, NH, HID, false, stream);
  launch_gemm(f1b, 128, WfbT, 128, fbuf, CH, T_TOK, CH, 128, false, stream);
  launch_gemm(g1b, 128, WgbT, 128, gateb, CH, T_TOK, CH, 128, true, stream);
  gamma_beta<<<dim3(T_TOK), 256, 0, stream>>>(fbuf, dt_bias, A_log, betab);

  // 4a) parallel WY prep: 4096 blocks (head x chunk)
  wy_prep<<<dim3(NH * NCH), 64, 0, stream>>>(qnb, knb, fbuf, betab,
                                             ktilT, Tmat, MBf, ecTb, e2Tb);
  // 4b) serial WY scan: 128 blocks (head x v-tile)
  scan_wy2<<<dim3(128), 64, 0, stream>>>(knb, qnb, vnb, ktilT, Tmat, MBf,
                                         ecTb, e2Tb, obuf);

  // 5) gated RMSNorm -> bf16 (ogb aliases qnb)
  postprocess<<<dim3(T_TOK), 256, 0, stream>>>(obuf, gateb, norm_w, ogb);

  // 6) output projection
  tr(Wo, Wbig, CH, HID);
  launch_gemm(ogb, CH, Wbig, CH, (float*)d_out, HID, T_TOK, HID, CH, false, stream);
}

// Round 9
// 1069.897 us; speedup vs baseline: 1.8928x; 1.0520x over previous
//
#include <hip/hip_runtime.h>
#include <hip/hip_bf16.h>
#include <math.h>

typedef __bf16 bf16_t;
typedef __bf16 bf16x8 __attribute__((ext_vector_type(8)));
typedef float  floatx4 __attribute__((ext_vector_type(4)));
typedef float  floatx2 __attribute__((ext_vector_type(2)));
typedef unsigned uintx4 __attribute__((ext_vector_type(4)));

constexpr int T_TOK = 4096;
constexpr int HID   = 2048;
constexpr int NH    = 16;
constexpr int DH    = 128;   // head dim
constexpr int CH    = 2048;  // NH*DH
constexpr int CHUNK = 16;
constexpr int NCH   = T_TOK / CHUNK;   // 256

// ---------------- cast fp32 -> bf16 (row-major preserved) ----------------
__global__ __launch_bounds__(256) void cast_to_bf16(const float* __restrict__ in,
                                                    bf16_t* __restrict__ out, int n) {
  int i = (blockIdx.x * 256 + threadIdx.x) * 8;
  if (i >= n) return;
  float4 a = *(const float4*)(in + i);
  float4 b = *(const float4*)(in + i + 4);
  bf16x8 o;
  o[0]=(bf16_t)a.x; o[1]=(bf16_t)a.y; o[2]=(bf16_t)a.z; o[3]=(bf16_t)a.w;
  o[4]=(bf16_t)b.x; o[5]=(bf16_t)b.y; o[6]=(bf16_t)b.z; o[7]=(bf16_t)b.w;
  *(bf16x8*)(out + i) = o;
}

// ---------------- transpose + cast: in fp32 [R,C] -> out bf16 [C,R] ----------------
__global__ __launch_bounds__(256) void transpose_cast(const float* __restrict__ in,
                                                      bf16_t* __restrict__ out, int R, int C) {
  __shared__ float tile[32][33];
  int tx = threadIdx.x & 31;
  int ty = threadIdx.x >> 5;  // 0..7
  int r0 = blockIdx.x * 32;
  int c0 = blockIdx.y * 32;
#pragma unroll
  for (int i = 0; i < 4; i++) {
    int r = ty + i * 8;
    float v = 0.f;
    if (r0 + r < R && c0 + tx < C) v = in[(size_t)(r0 + r) * C + (c0 + tx)];
    tile[r][tx] = v;
  }
  __syncthreads();
#pragma unroll
  for (int i = 0; i < 4; i++) {
    int cr = ty + i * 8;
    if (c0 + cr < C && r0 + tx < R)
      out[(size_t)(c0 + cr) * R + (r0 + tx)] = (bf16_t)tile[tx][cr];
  }
}

// ---------------- bf16 MFMA GEMM: C[M,N] = A[M,K] * Bt[N,K]^T ----------------
template<bool OUT_BF16>
__global__ __launch_bounds__(256) void gemm_bf16(
    const bf16_t* __restrict__ A, int lda,
    const bf16_t* __restrict__ Bt, int ldb,
    void* __restrict__ Cv, int ldc, int M, int N, int K) {
  __shared__ bf16_t sA[128][40];
  __shared__ bf16_t sB[128][40];
  const int tid  = threadIdx.x;
  const int bm0  = blockIdx.x * 128;
  const int bn0  = blockIdx.y * 128;
  const int wave = tid >> 6;
  const int lane = tid & 63;
  const int wm   = (wave & 1) * 64;
  const int wn   = (wave >> 1) * 64;
  const int fm   = lane & 15;
  const int kq   = lane >> 4;

  floatx4 acc[4][4];
#pragma unroll
  for (int mi = 0; mi < 4; mi++)
#pragma unroll
    for (int ni = 0; ni < 4; ni++)
      acc[mi][ni] = (floatx4){0.f, 0.f, 0.f, 0.f};

  const int sr = tid >> 2;
  const int sk = (tid & 3) * 8;
  const bool bval0 = (bn0 + sr) < N;
  const bool bval1 = (bn0 + sr + 64) < N;
  const bf16_t* Ag0 = A + (size_t)(bm0 + sr) * lda + sk;
  const bf16_t* Ag1 = Ag0 + (size_t)64 * lda;
  const bf16_t* Bg0 = Bt + (size_t)(bn0 + sr) * ldb + sk;
  const bf16_t* Bg1 = Bg0 + (size_t)64 * ldb;

  for (int k0 = 0; k0 < K; k0 += 32) {
    float4 a0 = *(const float4*)(Ag0 + k0);
    float4 a1 = *(const float4*)(Ag1 + k0);
    float4 b0 = bval0 ? *(const float4*)(Bg0 + k0) : make_float4(0.f, 0.f, 0.f, 0.f);
    float4 b1 = bval1 ? *(const float4*)(Bg1 + k0) : make_float4(0.f, 0.f, 0.f, 0.f);
    __syncthreads();
    *(float4*)(&sA[sr][sk])      = a0;
    *(float4*)(&sA[sr + 64][sk]) = a1;
    *(float4*)(&sB[sr][sk])      = b0;
    *(float4*)(&sB[sr + 64][sk]) = b1;
    __syncthreads();
    bf16x8 afr[4], bfr[4];
#pragma unroll
    for (int i = 0; i < 4; i++) {
      afr[i] = *(const bf16x8*)(&sA[wm + i * 16 + fm][kq * 8]);
      bfr[i] = *(const bf16x8*)(&sB[wn + i * 16 + fm][kq * 8]);
    }
#pragma unroll
    for (int mi = 0; mi < 4; mi++)
#pragma unroll
      for (int ni = 0; ni < 4; ni++)
        acc[mi][ni] = __builtin_amdgcn_mfma_f32_16x16x32_bf16(afr[mi], bfr[ni], acc[mi][ni], 0, 0, 0);
  }

  const int rr = (lane >> 4) * 4;
#pragma unroll
  for (int mi = 0; mi < 4; mi++) {
#pragma unroll
    for (int r = 0; r < 4; r++) {
      const int row = bm0 + wm + mi * 16 + rr + r;
#pragma unroll
      for (int ni = 0; ni < 4; ni++) {
        const int col = bn0 + wn + ni * 16 + fm;
        if (col < N) {
          if constexpr (OUT_BF16)
            ((bf16_t*)Cv)[(size_t)row * ldc + col] = (bf16_t)acc[mi][ni][r];
          else
            ((float*)Cv)[(size_t)row * ldc + col] = acc[mi][ni][r];
        }
      }
    }
  }
}

// ---------------- conv + silu (+ l2norm) : raw bf16 [T,CH] -> out bf16 [T,CH] ----------------
template<bool L2NORM>
__global__ __launch_bounds__(256) void conv_silu(
    const bf16_t* __restrict__ raw, const float* __restrict__ wconv,
    bf16_t* __restrict__ out) {
  const int t   = blockIdx.x;
  const int tid = threadIdx.x;
  const int c0  = tid * 8;

  float w[8][4];
#pragma unroll
  for (int j = 0; j < 8; j++) {
    float4 t0 = *(const float4*)(wconv + (size_t)(c0 + j) * 4);
    w[j][0] = t0.x; w[j][1] = t0.y; w[j][2] = t0.z; w[j][3] = t0.w;
  }
  float a[8] = {};
#pragma unroll
  for (int i = 0; i < 4; i++) {
    int tr = t - 3 + i;
    if (tr < 0) continue;
    bf16x8 xr = *(const bf16x8*)(raw + (size_t)tr * CH + c0);
#pragma unroll
    for (int j = 0; j < 8; j++) a[j] += w[j][i] * (float)xr[j];
  }
  float s = 0.f;
#pragma unroll
  for (int j = 0; j < 8; j++) {
    a[j] = a[j] / (1.f + expf(-a[j]));  // silu
    s += a[j] * a[j];
  }
  float rs = 1.f;
  if constexpr (L2NORM) {
#pragma unroll
    for (int m = 1; m < 16; m <<= 1) s += __shfl_xor(s, m);
    rs = rsqrtf(s + 1e-6f);
  }
  bf16x8 r;
#pragma unroll
  for (int j = 0; j < 8; j++) r[j] = (bf16_t)(a[j] * rs);
  *(bf16x8*)(out + (size_t)t * CH + c0) = r;
}

// ---------------- gamma: writes g = -a*softplus (LOG decay) + beta sigmoid ----------------
__global__ __launch_bounds__(256) void gamma_beta(
    float* __restrict__ f_gam, const float* __restrict__ dt_bias,
    const float* __restrict__ A_log, float* __restrict__ beta_io) {
  const int t   = blockIdx.x;
  const int tid = threadIdx.x;
  const int c0  = tid * 8;
  const int h   = c0 >> 7;
  const float a_h = expf(A_log[h]);
  const size_t o0 = (size_t)t * CH + c0;
  float fv[8], db[8];
  { float4 f0 = *(const float4*)(f_gam + o0);   float4 f1 = *(const float4*)(f_gam + o0 + 4);
    fv[0]=f0.x; fv[1]=f0.y; fv[2]=f0.z; fv[3]=f0.w; fv[4]=f1.x; fv[5]=f1.y; fv[6]=f1.z; fv[7]=f1.w;
    float4 d0 = *(const float4*)(dt_bias + c0); float4 d1 = *(const float4*)(dt_bias + c0 + 4);
    db[0]=d0.x; db[1]=d0.y; db[2]=d0.z; db[3]=d0.w; db[4]=d1.x; db[5]=d1.y; db[6]=d1.z; db[7]=d1.w; }
  float og[8];
#pragma unroll
  for (int j = 0; j < 8; j++) {
    float f = fv[j] + db[j];
    float sp = (f > 20.f) ? f : log1pf(expf(f));
    og[j] = -a_h * sp;                       // g (log-decay), exp applied in prep
  }
  *(float4*)(f_gam + o0)     = make_float4(og[0], og[1], og[2], og[3]);
  *(float4*)(f_gam + o0 + 4) = make_float4(og[4], og[5], og[6], og[7]);
  if (tid < NH) {
    float b = beta_io[(size_t)t * NH + tid];
    beta_io[(size_t)t * NH + tid] = 1.f / (1.f + expf(-b));
  }
}

// ---------------- helpers for WY kernels ----------------
template<int IMM>
__device__ __forceinline__ float swzf(float x) {
  return __builtin_bit_cast(float, __builtin_amdgcn_ds_swizzle(__builtin_bit_cast(int, x), IMM));
}
template<int CTRL>
__device__ __forceinline__ float dppadd(float x) {
  int v = __builtin_amdgcn_update_dpp(0, __builtin_bit_cast(int, x), CTRL, 0xF, 0xF, true);
  return x + __builtin_bit_cast(float, v);
}
__device__ __forceinline__ float cumsum16(float x) {  // inclusive scan within 16-lane row
  x = dppadd<0x111>(x);  // row_shr:1
  x = dppadd<0x112>(x);  // row_shr:2
  x = dppadd<0x114>(x);  // row_shr:4
  x = dppadd<0x118>(x);  // row_shr:8
  return x;
}
__device__ __forceinline__ float bperm(int lane, float x) {
  return __builtin_bit_cast(float, __builtin_amdgcn_ds_bpermute(lane << 2, __builtin_bit_cast(int, x)));
}
__device__ __forceinline__ floatx2 bfpair(unsigned u) {
  floatx2 r;
  r[0] = __builtin_bit_cast(float, u << 16);
  r[1] = __builtin_bit_cast(float, u & 0xFFFF0000u);
  return r;
}

// ---------------- WY prep: fully parallel over (head, chunk) ----------------
__global__ __launch_bounds__(64) void wy_prep(
    bf16_t* __restrict__ qn, bf16_t* __restrict__ kn,
    const float* __restrict__ gg, const float* __restrict__ beta,
    bf16_t* __restrict__ ktilT, float* __restrict__ Tm,
    bf16_t* __restrict__ MBf, float* __restrict__ ecT, float* __restrict__ e2T) {
  const int hc = blockIdx.x;        // h*NCH + c
  const int h  = hc >> 8;           // NCH = 256
  const int c  = hc & 255;
  const int l  = threadIdx.x;
  const int tl = l & 15;            // t within chunk
  const int gr = l >> 4;            // 0..3

  __shared__ bf16_t KldsT[128][24];  // ktil^T [k][t], 48B rows (16B-aligned)
  __shared__ float  Wlds[16][17];    // W[t][s]
  __shared__ float  Mlds[16][17];    // masked M[t][s]
  __shared__ float  eclds[128], e2lds[128];
  __shared__ float  blds[16];

  const int kb0 = h * DH + gr * 8;
  const size_t rowoff = (size_t)(c * CHUNK + tl) * CH;

  if (gr == 0) blds[tl] = beta[(size_t)(c * CHUNK + tl) * NH + h];

  floatx4 wt = (floatx4){0.f, 0.f, 0.f, 0.f};
  floatx4 m  = (floatx4){0.f, 0.f, 0.f, 0.f};
  bf16x8 khs[4], qhs[4];
#pragma unroll
  for (int kb = 0; kb < 4; kb++) {
    const int ke = kb0 + kb * 32;
    float4 ga = *(const float4*)(gg + rowoff + ke);
    float4 gb = *(const float4*)(gg + rowoff + ke + 4);
    float cm[8] = {ga.x, ga.y, ga.z, ga.w, gb.x, gb.y, gb.z, gb.w};
    float lamh[8], lamt[8], ec[8], e2[8];
#pragma unroll
    for (int j = 0; j < 8; j++) {
      float cs   = cumsum16(cm[j]);                 // inclusive cumg over t
      float cmid = swzf<(7 << 5) | 0x10>(cs);       // c = cumg at t=7
      lamh[j] = __expf(cs - cmid);
      lamt[j] = __expf(cmid - cs);
      ec[j]   = __expf(cmid);
      e2[j]   = swzf<(15 << 5) | 0x10>(lamh[j]);    // exp(cumg15 - c)
    }
    if (tl == 0) {
#pragma unroll
      for (int j = 0; j < 8; j++) {
        eclds[kb * 32 + gr * 8 + j] = ec[j];
        e2lds[kb * 32 + gr * 8 + j] = e2[j];
      }
    }
    uint4 kr = *(const uint4*)(kn + rowoff + ke);
    uint4 qr = *(const uint4*)(qn + rowoff + ke);
    float kf[8], qf[8];
    { floatx2 a0 = bfpair(kr.x), a1 = bfpair(kr.y), a2 = bfpair(kr.z), a3 = bfpair(kr.w);
      kf[0]=a0[0];kf[1]=a0[1];kf[2]=a1[0];kf[3]=a1[1];kf[4]=a2[0];kf[5]=a2[1];kf[6]=a3[0];kf[7]=a3[1];
      floatx2 b0 = bfpair(qr.x), b1 = bfpair(qr.y), b2 = bfpair(qr.z), b3 = bfpair(qr.w);
      qf[0]=b0[0];qf[1]=b0[1];qf[2]=b1[0];qf[3]=b1[1];qf[4]=b2[0];qf[5]=b2[1];qf[6]=b3[0];qf[7]=b3[1]; }
    bf16x8 khat, ktil, qhat;
#pragma unroll
    for (int j = 0; j < 8; j++) {
      khat[j] = (bf16_t)(kf[j] * lamh[j]);
      ktil[j] = (bf16_t)(kf[j] * lamt[j]);
      qhat[j] = (bf16_t)(qf[j] * lamh[j]);
      khs[kb][j] = (bf16_t)(kf[j] * lamh[j] * ec[j]);   // k * exp(cumg)
      qhs[kb][j] = (bf16_t)(qf[j] * lamh[j] * ec[j]);
    }
    wt = __builtin_amdgcn_mfma_f32_16x16x32_bf16(ktil, khat, wt, 0, 0, 0);  // W^T
    m  = __builtin_amdgcn_mfma_f32_16x16x32_bf16(qhat, ktil, m,  0, 0, 0);  // M
#pragma unroll
    for (int j = 0; j < 8; j++) KldsT[kb * 32 + gr * 8 + j][tl] = ktil[j];
  }
  // in-place khs/qhs stores (all reads of this slice completed above)
#pragma unroll
  for (int kb = 0; kb < 4; kb++) {
    *(uint4*)(kn + rowoff + kb0 + kb * 32) = __builtin_bit_cast(uint4, khs[kb]);
    *(uint4*)(qn + rowoff + kb0 + kb * 32) = __builtin_bit_cast(uint4, qhs[kb]);
  }
  // W, masked M to LDS
#pragma unroll
  for (int ri = 0; ri < 4; ri++) {
    Wlds[tl][4 * gr + ri] = wt[ri];                               // W[t=tl][s=4gr+ri]
    Mlds[4 * gr + ri][tl] = (4 * gr + ri >= tl) ? m[ri] : 0.f;    // M[t][s], tril incl
  }
  // T solve (exact f32): X = inv(I + tril_strict(diag(b)W)); T[t][j] = X[t][j]*b_j
  {
    const int j = tl;
    float x[16];
#pragma unroll
    for (int t = 0; t < 16; t++) {
      float a = 0.f;
#pragma unroll
      for (int s = 0; s < 16; s++)
        if (s < t) a = fmaf(Wlds[t][s], x[s], a);
      x[t] = (t == j) ? 1.f : ((t > j) ? -blds[t] * a : 0.f);
    }
    if (gr == 0) {
      const float bj = blds[j];
#pragma unroll
      for (int t = 0; t < 16; t++)
        Tm[((size_t)hc * 16 + t) * 16 + j] = x[t] * bj;
    }
  }
  // masked-M as ready B-frag (col=t=tl, elems s=gr*8+jj; gr>=2 zero)
  {
    uint4 mbo = {0, 0, 0, 0};
    if (gr < 2) {
      bf16x8 mm;
#pragma unroll
      for (int jj = 0; jj < 8; jj++) mm[jj] = (bf16_t)Mlds[tl][gr * 8 + jj];
      mbo = __builtin_bit_cast(uint4, mm);
    }
    ((uint4*)MBf)[(size_t)hc * 64 + l] = mbo;
  }
  // ktil^T -> global (coalesced rows of 16 bf16)
  for (int i = l; i < 128; i += 64) {
    uint4 a0 = *(const uint4*)&KldsT[i][0];
    uint4 a1 = *(const uint4*)&KldsT[i][8];
    bf16_t* dst = ktilT + ((size_t)hc * 128 + i) * 16;
    *(uint4*)dst = a0;
    *(uint4*)(dst + 8) = a1;
  }
  // ec/e2 transposed for float4 loads: [tl][kt]
  for (int i = l; i < 128; i += 64) {
    ecT[(size_t)hc * 128 + (i & 15) * 8 + (i >> 4)] = eclds[i];
    e2T[(size_t)hc * 128 + (i & 15) * 8 + (i >> 4)] = e2lds[i];
  }
}

// ---------------- serial WY scan, wave-specialized producer/consumer ----------------
// 128 blocks = (head, v-tile); 128 threads = 2 waves. Wave 0 computes chunk c
// from LDS-staged inputs; wave 1 concurrently loads chunk c+1 global->regs->LDS
// (double buffer). The ~900cy HBM latency lands on the producer wave, OFF the
// serial chain — the mechanism regalloc cannot collapse (round 2-6 lesson).
// Staging arrays are field-major [2][n][64] of 16B -> conflict-free b128.
// gr>=2 lanes' ktil slots are loaded as duplicates of gr&1 (valid finite bf16;
// A-operand dva is zero there, and 0*finite=0 — garbage could be NaN).
__global__ __launch_bounds__(128, 1) void scan_wy3(
    const bf16_t* __restrict__ khsG, const bf16_t* __restrict__ qhsG,
    const bf16_t* __restrict__ vn, const bf16_t* __restrict__ ktilT,
    const float* __restrict__ Tm, const bf16_t* __restrict__ MBf,
    const float* __restrict__ ecT, const float* __restrict__ e2T,
    float* __restrict__ o) {
  const int h   = blockIdx.x >> 3;   // 16 heads
  const int vt  = blockIdx.x & 7;    // 8 v-tiles
  const int tid = threadIdx.x;
  const int wid = tid >> 6;          // 0 = consumer, 1 = producer
  const int l   = tid & 63;
  const int tl  = l & 15;
  const int gr  = l >> 4;

  __shared__ uint4   sKQ[2][8][64];   // khs kb0..3, qhs kb0..3  (16 KiB)
  __shared__ floatx4 sT[2][4][64];    // T rows                   (8 KiB)
  __shared__ uint4   sMB[2][64];      // masked-M B-frag          (2 KiB)
  __shared__ uint4   sKT[2][8][64];   // ktil B-frags             (16 KiB)
  __shared__ floatx4 sEC[2][4][64];   // ec0,ec1,e20,e21          (8 KiB)
  __shared__ uint2   sV[2][64];       // v                        (1 KiB)
  __shared__ float   SldsT[16][132];  // S^T [v][k]               (8.25 KiB)
  __shared__ float   DVlds[16][17];   // dv [t][v]

  const int kb0 = h * DH + gr * 8;
  const int vb0 = h * DH + vt * 16 + gr * 4;
  const size_t hcBase = (size_t)h * NCH;
  constexpr float scale = 0.08838834764831845f;

  auto produce = [&](int c, int b) {
    const size_t rowoff = (size_t)(c * CHUNK + tl) * CH;
    const size_t hc = hcBase + c;
    uint4 kq[8];
#pragma unroll
    for (int kb = 0; kb < 4; kb++) {
      kq[kb]     = *(const uint4*)(khsG + rowoff + kb0 + kb * 32);
      kq[4 + kb] = *(const uint4*)(qhsG + rowoff + kb0 + kb * 32);
    }
    const float* Trp = Tm + (hc * 16 + tl) * 16;
    floatx4 Tv[4];
#pragma unroll
    for (int j = 0; j < 4; j++) Tv[j] = *(const floatx4*)(Trp + 4 * j);
    uint4 mbv = ((const uint4*)MBf)[hc * 64 + l];
    const int g2 = gr & 1;
    uint4 ktv[8];
#pragma unroll
    for (int kt = 0; kt < 8; kt++)
      ktv[kt] = *(const uint4*)(ktilT + (hc * 128 + kt * 16 + tl) * 16 + g2 * 8);
    floatx4 ecv[4];
    ecv[0] = *(const floatx4*)(ecT + hc * 128 + tl * 8);
    ecv[1] = *(const floatx4*)(ecT + hc * 128 + tl * 8 + 4);
    ecv[2] = *(const floatx4*)(e2T + hc * 128 + tl * 8);
    ecv[3] = *(const floatx4*)(e2T + hc * 128 + tl * 8 + 4);
    uint2 vv = *(const uint2*)(vn + rowoff + vb0);
#pragma unroll
    for (int i = 0; i < 8; i++) sKQ[b][i][l] = kq[i];
#pragma unroll
    for (int j = 0; j < 4; j++) sT[b][j][l] = Tv[j];
    sMB[b][l] = mbv;
#pragma unroll
    for (int i = 0; i < 8; i++) sKT[b][i][l] = ktv[i];
#pragma unroll
    for (int j = 0; j < 4; j++) sEC[b][j][l] = ecv[j];
    sV[b][l] = vv;
  };

  float S[8][4];
#pragma unroll
  for (int kt = 0; kt < 8; kt++)
#pragma unroll
    for (int ri = 0; ri < 4; ri++) S[kt][ri] = 0.f;

  if (wid == 1) {
    produce(0, 0);
  } else {
    for (int i = l; i < 16 * 132; i += 64) (&SldsT[0][0])[i] = 0.f;
  }
  __syncthreads();

  int cur = 0;
  for (int c = 0; c < NCH; ++c) {
    if (wid == 1) {
      produce(c + 1 < NCH ? c + 1 : NCH - 1, cur ^ 1);
    } else {
      const size_t rowoff = (size_t)(c * CHUNK + tl) * CH;
      // ---- P, O1 from S0 ----
      floatx4 p  = (floatx4){0.f, 0.f, 0.f, 0.f};
      floatx4 o1 = (floatx4){0.f, 0.f, 0.f, 0.f};
#pragma unroll
      for (int kb = 0; kb < 4; kb++) {
        float4 sa = *(const float4*)(&SldsT[tl][kb * 32 + gr * 8]);
        float4 sb = *(const float4*)(&SldsT[tl][kb * 32 + gr * 8 + 4]);
        bf16x8 s0a;
        s0a[0]=(bf16_t)sa.x; s0a[1]=(bf16_t)sa.y; s0a[2]=(bf16_t)sa.z; s0a[3]=(bf16_t)sa.w;
        s0a[4]=(bf16_t)sb.x; s0a[5]=(bf16_t)sb.y; s0a[6]=(bf16_t)sb.z; s0a[7]=(bf16_t)sb.w;
        p  = __builtin_amdgcn_mfma_f32_16x16x32_bf16(s0a, __builtin_bit_cast(bf16x8, sKQ[cur][kb][l]), p,  0, 0, 0);
        o1 = __builtin_amdgcn_mfma_f32_16x16x32_bf16(s0a, __builtin_bit_cast(bf16x8, sKQ[cur][4 + kb][l]), o1, 0, 0, 0);
      }
      // ---- V' = V - P ; DV = T*V' (pipelined bperm, exact f32 T) ----
      float acc[4];
      { uint2 vr = sV[cur][l];
        floatx2 v01 = bfpair(vr.x), v23 = bfpair(vr.y);
        acc[0] = v01[0] - p[0]; acc[1] = v01[1] - p[1];
        acc[2] = v23[0] - p[2]; acc[3] = v23[1] - p[3]; }
      floatx4 T0 = sT[cur][0][l], T1 = sT[cur][1][l], T2 = sT[cur][2][l], T3 = sT[cur][3][l];
      float dv[4] = {0.f, 0.f, 0.f, 0.f};
#pragma unroll
      for (int s = 0; s < 16; s++) {
        const float ts = (s < 4) ? T0[s] : (s < 8) ? T1[s - 4] : (s < 12) ? T2[s - 8] : T3[s - 12];
#pragma unroll
        for (int ri = 0; ri < 4; ri++)
          dv[ri] = fmaf(ts, bperm((gr << 4) | s, acc[ri]), dv[ri]);
      }
#pragma unroll
      for (int ri = 0; ri < 4; ri++) DVlds[tl][4 * gr + ri] = dv[ri];
      bf16x8 dva = {};
      if (gr < 2) {
#pragma unroll
        for (int jj = 0; jj < 8; jj++) dva[jj] = (bf16_t)DVlds[gr * 8 + jj][tl];
      }
      // ---- O2, store O ----
      floatx4 o2 = __builtin_amdgcn_mfma_f32_16x16x32_bf16(
          dva, __builtin_bit_cast(bf16x8, sMB[cur][l]), (floatx4){0.f, 0.f, 0.f, 0.f}, 0, 0, 0);
      { float4 ov = make_float4((o1[0] + o2[0]) * scale, (o1[1] + o2[1]) * scale,
                                (o1[2] + o2[2]) * scale, (o1[3] + o2[3]) * scale);
        *(float4*)(o + rowoff + vb0) = ov; }
      // ---- S update: S' = e2*(ec*S0 + DV^T K~) ----
      floatx4 ec0 = sEC[cur][0][l], ec1 = sEC[cur][1][l];
      floatx4 e20 = sEC[cur][2][l], e21 = sEC[cur][3][l];
#pragma unroll
      for (int kt = 0; kt < 8; kt++) {
        const float ecK = (kt < 4) ? ec0[kt] : ec1[kt - 4];
        const float e2K = (kt < 4) ? e20[kt] : e21[kt - 4];
        floatx4 sa;
#pragma unroll
        for (int ri = 0; ri < 4; ri++) sa[ri] = ecK * S[kt][ri];
        sa = __builtin_amdgcn_mfma_f32_16x16x32_bf16(
            dva, __builtin_bit_cast(bf16x8, sKT[cur][kt][l]), sa, 0, 0, 0);
#pragma unroll
        for (int ri = 0; ri < 4; ri++) S[kt][ri] = e2K * sa[ri];
      }
      // ---- publish S^T for next chunk ----
#pragma unroll
      for (int kt = 0; kt < 8; kt++)
#pragma unroll
        for (int ri = 0; ri < 4; ri++)
          SldsT[4 * gr + ri][kt * 16 + tl] = S[kt][ri];
    }
    __syncthreads();
    cur ^= 1;
  }
}

// ---------------- postprocess: RMSNorm * norm_w * silu(gate bf16) -> bf16 ----------------
__global__ __launch_bounds__(256) void postprocess(
    const float* __restrict__ o, const bf16_t* __restrict__ gate,
    const float* __restrict__ norm_w, bf16_t* __restrict__ og) {
  const int t = blockIdx.x, tid = threadIdx.x;
  const int c0 = tid * 8, d0 = c0 & 127;
  const size_t o0 = (size_t)t * CH + c0;
  float ov[8], gv[8], nw[8];
  { float4 a = *(const float4*)(o + o0);    float4 b = *(const float4*)(o + o0 + 4);
    ov[0]=a.x; ov[1]=a.y; ov[2]=a.z; ov[3]=a.w; ov[4]=b.x; ov[5]=b.y; ov[6]=b.z; ov[7]=b.w;
    bf16x8 g8 = *(const bf16x8*)(gate + o0);
    for (int j = 0; j < 8; j++) gv[j] = (float)g8[j];
    float4 e = *(const float4*)(norm_w + d0); float4 f = *(const float4*)(norm_w + d0 + 4);
    nw[0]=e.x; nw[1]=e.y; nw[2]=e.z; nw[3]=e.w; nw[4]=f.x; nw[5]=f.y; nw[6]=f.z; nw[7]=f.w; }
  float ss = 0.f;
#pragma unroll
  for (int j = 0; j < 8; j++) ss += ov[j] * ov[j];
#pragma unroll
  for (int m = 1; m < 16; m <<= 1) ss += __shfl_xor(ss, m);
  const float rs = rsqrtf(ss * (1.f / 128.f) + 1e-6f);
  bf16x8 r;
#pragma unroll
  for (int j = 0; j < 8; j++) {
    float g = gv[j];
    float val = ov[j] * rs * nw[j] * (g / (1.f + expf(-g)));
    r[j] = (bf16_t)val;
  }
  *(bf16x8*)(og + o0) = r;
}

// ---------------- host launcher ----------------
static inline void launch_gemm(const bf16_t* A, int lda, const bf16_t* Bt, int ldb,
                               void* C, int ldc, int M, int N, int K, bool obf16,
                               hipStream_t s) {
  dim3 grid(M / 128, (N + 127) / 128);
  if (obf16) gemm_bf16<true><<<grid, 256, 0, s>>>(A, lda, Bt, ldb, C, ldc, M, N, K);
  else       gemm_bf16<false><<<grid, 256, 0, s>>>(A, lda, Bt, ldb, C, ldc, M, N, K);
}

extern "C" void kernel_launch(void* const* d_in, const int* in_sizes, int n_in,
                              void* d_out, int out_size, void* d_ws, size_t ws_size,
                              hipStream_t stream) {
  const float* x       = (const float*)d_in[0];
  const float* Wq      = (const float*)d_in[1];
  const float* Wk      = (const float*)d_in[2];
  const float* Wv      = (const float*)d_in[3];
  const float* wqc     = (const float*)d_in[4];
  const float* wkc     = (const float*)d_in[5];
  const float* wvc     = (const float*)d_in[6];
  const float* A_log   = (const float*)d_in[7];
  const float* dt_bias = (const float*)d_in[8];
  const float* Wfa     = (const float*)d_in[9];
  const float* Wfb     = (const float*)d_in[10];
  const float* Wb      = (const float*)d_in[11];
  const float* Wga     = (const float*)d_in[12];
  const float* Wgb     = (const float*)d_in[13];
  const float* norm_w  = (const float*)d_in[14];
  const float* Wo      = (const float*)d_in[15];

  char* w = (char*)d_ws;
  size_t off = 0;
  auto give = [&](size_t bytes) -> void* {
    size_t cur = off;
    off = (off + bytes + 255) & ~(size_t)255;
    return (void*)(w + cur);
  };
  bf16_t* Wbig = (bf16_t*)give((size_t)CH * HID * 2);   // reused: WqT,WkT,WvT,WoT
  bf16_t* WfaT = (bf16_t*)give((size_t)128 * HID * 2);
  bf16_t* WgaT = (bf16_t*)give((size_t)128 * HID * 2);
  bf16_t* WfbT = (bf16_t*)give((size_t)CH * 128 * 2);
  bf16_t* WgbT = (bf16_t*)give((size_t)CH * 128 * 2);
  bf16_t* WbT  = (bf16_t*)give((size_t)NH * HID * 2);
  bf16_t* Ax   = (bf16_t*)give((size_t)T_TOK * HID * 2);  // 16 MiB
  bf16_t* raw0 = (bf16_t*)give((size_t)T_TOK * CH * 2);   // 16 MiB, reused q/k/v raw
  bf16_t* qnb  = (bf16_t*)give((size_t)T_TOK * CH * 2);
  bf16_t* knb  = (bf16_t*)give((size_t)T_TOK * CH * 2);
  bf16_t* vnb  = (bf16_t*)give((size_t)T_TOK * CH * 2);
  bf16_t* f1b  = (bf16_t*)give((size_t)T_TOK * 128 * 2);
  bf16_t* g1b  = (bf16_t*)give((size_t)T_TOK * 128 * 2);
  float*  fbuf = (float*)give((size_t)T_TOK * CH * 4);    // f_pre -> g (log decay) in-place
  bf16_t* gateb= (bf16_t*)give((size_t)T_TOK * CH * 2);
  float*  betab= (float*)give((size_t)T_TOK * NH * 4);
  // WY precompute buffers (+28 MiB)
  bf16_t* ktilT= (bf16_t*)give((size_t)NH * NCH * 128 * 16 * 2);  // 16 MiB
  float*  Tmat = (float*)give((size_t)NH * NCH * 256 * 4);        // 4 MiB
  bf16_t* MBf  = (bf16_t*)give((size_t)NH * NCH * 64 * 8 * 2);    // 4 MiB
  float*  ecTb = (float*)give((size_t)NH * NCH * 128 * 4);        // 2 MiB
  float*  e2Tb = (float*)give((size_t)NH * NCH * 128 * 4);        // 2 MiB
  // aliases over dead regions:
  float*  obuf = (float*)Ax;    // 32 MiB = Ax(16)+raw0(16), both dead before scan
  bf16_t* ogb  = qnb;           // qnb dead after scan

  auto tr = [&](const float* in, bf16_t* out, int R, int C) {
    transpose_cast<<<dim3((R + 31) / 32, (C + 31) / 32), 256, 0, stream>>>(in, out, R, C);
  };

  // 1) cast x, small weight transposes
  cast_to_bf16<<<dim3((T_TOK * HID) / 2048), 256, 0, stream>>>(x, Ax, T_TOK * HID);
  tr(Wfa, WfaT, HID, 128); tr(Wga, WgaT, HID, 128);
  tr(Wfb, WfbT, 128, CH);  tr(Wgb, WgbT, 128, CH);
  tr(Wb, WbT, HID, NH);

  // 2) q/k/v: transpose weight -> GEMM -> conv+silu(+l2norm), reusing Wbig and raw0
  tr(Wq, Wbig, HID, CH);
  launch_gemm(Ax, HID, Wbig, HID, raw0, CH, T_TOK, CH, HID, true, stream);
  conv_silu<true><<<dim3(T_TOK), 256, 0, stream>>>(raw0, wqc, qnb);
  tr(Wk, Wbig, HID, CH);
  launch_gemm(Ax, HID, Wbig, HID, raw0, CH, T_TOK, CH, HID, true, stream);
  conv_silu<true><<<dim3(T_TOK), 256, 0, stream>>>(raw0, wkc, knb);
  tr(Wv, Wbig, HID, CH);
  launch_gemm(Ax, HID, Wbig, HID, raw0, CH, T_TOK, CH, HID, true, stream);
  conv_silu<false><<<dim3(T_TOK), 256, 0, stream>>>(raw0, wvc, vnb);

  // 3) f/g/beta chains
  launch_gemm(Ax, HID, WfaT, HID, f1b, 128, T_TOK, 128, HID, true, stream);
  launch_gemm(Ax, HID, WgaT, HID, g1b, 128, T_TOK, 128, HID, true, stream);
  launch_gemm(Ax, HID, WbT, HID, betab, NH, T_TOK, NH, HID, false, stream);
  launch_gemm(f1b, 128, WfbT, 128, fbuf, CH, T_TOK, CH, 128, false, stream);
  launch_gemm(g1b, 128, WgbT, 128, gateb, CH, T_TOK, CH, 128, true, stream);
  gamma_beta<<<dim3(T_TOK), 256, 0, stream>>>(fbuf, dt_bias, A_log, betab);

  // 4a) parallel WY prep: 4096 blocks (head x chunk)
  wy_prep<<<dim3(NH * NCH), 64, 0, stream>>>(qnb, knb, fbuf, betab,
                                             ktilT, Tmat, MBf, ecTb, e2Tb);
  // 4b) serial WY scan: 128 blocks (head x v-tile) x 2 waves (compute + producer)
  scan_wy3<<<dim3(128), 128, 0, stream>>>(knb, qnb, vnb, ktilT, Tmat, MBf,
                                          ecTb, e2Tb, obuf);

  // 5) gated RMSNorm -> bf16 (ogb aliases qnb)
  postprocess<<<dim3(T_TOK), 256, 0, stream>>>(obuf, gateb, norm_w, ogb);

  // 6) output projection
  tr(Wo, Wbig, CH, HID);
  launch_gemm(ogb, CH, Wbig, CH, (float*)d_out, HID, T_TOK, HID, CH, false, stream);
}

// Round 10
// 1025.095 us; speedup vs baseline: 1.9756x; 1.0437x over previous
//
#include <hip/hip_runtime.h>
#include <hip/hip_bf16.h>
#include <math.h>

typedef __bf16 bf16_t;
typedef __bf16 bf16x8 __attribute__((ext_vector_type(8)));
typedef float  floatx4 __attribute__((ext_vector_type(4)));
typedef float  floatx2 __attribute__((ext_vector_type(2)));
typedef unsigned uintx4 __attribute__((ext_vector_type(4)));

constexpr int T_TOK = 4096;
constexpr int HID   = 2048;
constexpr int NH    = 16;
constexpr int DH    = 128;   // head dim
constexpr int CH    = 2048;  // NH*DH
constexpr int CHUNK = 16;
constexpr int NCH   = T_TOK / CHUNK;   // 256

// ---------------- cast fp32 -> bf16 (row-major preserved) ----------------
__global__ __launch_bounds__(256) void cast_to_bf16(const float* __restrict__ in,
                                                    bf16_t* __restrict__ out, int n) {
  int i = (blockIdx.x * 256 + threadIdx.x) * 8;
  if (i >= n) return;
  float4 a = *(const float4*)(in + i);
  float4 b = *(const float4*)(in + i + 4);
  bf16x8 o;
  o[0]=(bf16_t)a.x; o[1]=(bf16_t)a.y; o[2]=(bf16_t)a.z; o[3]=(bf16_t)a.w;
  o[4]=(bf16_t)b.x; o[5]=(bf16_t)b.y; o[6]=(bf16_t)b.z; o[7]=(bf16_t)b.w;
  *(bf16x8*)(out + i) = o;
}

// ---------------- transpose + cast: in fp32 [R,C] -> out bf16 [C,R] ----------------
__global__ __launch_bounds__(256) void transpose_cast(const float* __restrict__ in,
                                                      bf16_t* __restrict__ out, int R, int C) {
  __shared__ float tile[32][33];
  int tx = threadIdx.x & 31;
  int ty = threadIdx.x >> 5;  // 0..7
  int r0 = blockIdx.x * 32;
  int c0 = blockIdx.y * 32;
#pragma unroll
  for (int i = 0; i < 4; i++) {
    int r = ty + i * 8;
    float v = 0.f;
    if (r0 + r < R && c0 + tx < C) v = in[(size_t)(r0 + r) * C + (c0 + tx)];
    tile[r][tx] = v;
  }
  __syncthreads();
#pragma unroll
  for (int i = 0; i < 4; i++) {
    int cr = ty + i * 8;
    if (c0 + cr < C && r0 + tx < R)
      out[(size_t)(c0 + cr) * R + (r0 + tx)] = (bf16_t)tile[tx][cr];
  }
}

// ---------------- bf16 MFMA GEMM (general, bounds-checked): C = A * Bt^T ----------------
template<bool OUT_BF16>
__global__ __launch_bounds__(256) void gemm_bf16(
    const bf16_t* __restrict__ A, int lda,
    const bf16_t* __restrict__ Bt, int ldb,
    void* __restrict__ Cv, int ldc, int M, int N, int K) {
  __shared__ bf16_t sA[128][40];
  __shared__ bf16_t sB[128][40];
  const int tid  = threadIdx.x;
  const int bm0  = blockIdx.x * 128;
  const int bn0  = blockIdx.y * 128;
  const int wave = tid >> 6;
  const int lane = tid & 63;
  const int wm   = (wave & 1) * 64;
  const int wn   = (wave >> 1) * 64;
  const int fm   = lane & 15;
  const int kq   = lane >> 4;

  floatx4 acc[4][4];
#pragma unroll
  for (int mi = 0; mi < 4; mi++)
#pragma unroll
    for (int ni = 0; ni < 4; ni++)
      acc[mi][ni] = (floatx4){0.f, 0.f, 0.f, 0.f};

  const int sr = tid >> 2;
  const int sk = (tid & 3) * 8;
  const bool bval0 = (bn0 + sr) < N;
  const bool bval1 = (bn0 + sr + 64) < N;
  const bf16_t* Ag0 = A + (size_t)(bm0 + sr) * lda + sk;
  const bf16_t* Ag1 = Ag0 + (size_t)64 * lda;
  const bf16_t* Bg0 = Bt + (size_t)(bn0 + sr) * ldb + sk;
  const bf16_t* Bg1 = Bg0 + (size_t)64 * ldb;

  for (int k0 = 0; k0 < K; k0 += 32) {
    float4 a0 = *(const float4*)(Ag0 + k0);
    float4 a1 = *(const float4*)(Ag1 + k0);
    float4 b0 = bval0 ? *(const float4*)(Bg0 + k0) : make_float4(0.f, 0.f, 0.f, 0.f);
    float4 b1 = bval1 ? *(const float4*)(Bg1 + k0) : make_float4(0.f, 0.f, 0.f, 0.f);
    __syncthreads();
    *(float4*)(&sA[sr][sk])      = a0;
    *(float4*)(&sA[sr + 64][sk]) = a1;
    *(float4*)(&sB[sr][sk])      = b0;
    *(float4*)(&sB[sr + 64][sk]) = b1;
    __syncthreads();
    bf16x8 afr[4], bfr[4];
#pragma unroll
    for (int i = 0; i < 4; i++) {
      afr[i] = *(const bf16x8*)(&sA[wm + i * 16 + fm][kq * 8]);
      bfr[i] = *(const bf16x8*)(&sB[wn + i * 16 + fm][kq * 8]);
    }
#pragma unroll
    for (int mi = 0; mi < 4; mi++)
#pragma unroll
      for (int ni = 0; ni < 4; ni++)
        acc[mi][ni] = __builtin_amdgcn_mfma_f32_16x16x32_bf16(afr[mi], bfr[ni], acc[mi][ni], 0, 0, 0);
  }

  const int rr = (lane >> 4) * 4;
#pragma unroll
  for (int mi = 0; mi < 4; mi++) {
#pragma unroll
    for (int r = 0; r < 4; r++) {
      const int row = bm0 + wm + mi * 16 + rr + r;
#pragma unroll
      for (int ni = 0; ni < 4; ni++) {
        const int col = bn0 + wn + ni * 16 + fm;
        if (col < N) {
          if constexpr (OUT_BF16)
            ((bf16_t*)Cv)[(size_t)row * ldc + col] = (bf16_t)acc[mi][ni][r];
          else
            ((float*)Cv)[(size_t)row * ldc + col] = acc[mi][ni][r];
        }
      }
    }
  }
}

// ---------------- fast GEMM (m97 recipe): global_load_lds w16, linear LDS ----------------
// Requires M%128==0, N%128==0, K%32==0 (no masking). Dest of global_load_lds is
// wave-uniform slab base + lane*16B; our (sr=tid>>2, sk=(tid&3)*8) mapping is
// exactly lane-linear within each wave's 16-row slab. 2 barriers per K-step;
// compiler emits s_waitcnt vmcnt(0) before s_barrier (guide §5), making the
// staged data visible. Guide ladder: reg-staged 517 TF -> gload_lds 874 TF.
__device__ __forceinline__ void gload_lds16(const bf16_t* g, bf16_t* l) {
  __builtin_amdgcn_global_load_lds(
      (const __attribute__((address_space(1))) void*)g,
      (__attribute__((address_space(3))) void*)l, 16, 0, 0);
}

template<bool OUT_BF16>
__global__ __launch_bounds__(256) void gemm_bf16_lds(
    const bf16_t* __restrict__ A, int lda,
    const bf16_t* __restrict__ Bt, int ldb,
    void* __restrict__ Cv, int ldc, int M, int N, int K) {
  __shared__ bf16_t sA[128][32];
  __shared__ bf16_t sB[128][32];
  const int tid  = threadIdx.x;
  const int bm0  = blockIdx.x * 128;
  const int bn0  = blockIdx.y * 128;
  const int wave = tid >> 6;
  const int lane = tid & 63;
  const int wm   = (wave & 1) * 64;
  const int wn   = (wave >> 1) * 64;
  const int fm   = lane & 15;
  const int kq   = lane >> 4;

  floatx4 acc[4][4];
#pragma unroll
  for (int mi = 0; mi < 4; mi++)
#pragma unroll
    for (int ni = 0; ni < 4; ni++)
      acc[mi][ni] = (floatx4){0.f, 0.f, 0.f, 0.f};

  const int sr = tid >> 2;          // 0..63
  const int sk = (tid & 3) * 8;
  const bf16_t* Ag0 = A + (size_t)(bm0 + sr) * lda + sk;
  const bf16_t* Ag1 = Ag0 + (size_t)64 * lda;
  const bf16_t* Bg0 = Bt + (size_t)(bn0 + sr) * ldb + sk;
  const bf16_t* Bg1 = Bg0 + (size_t)64 * ldb;
  bf16_t* ldsA0 = &sA[16 * wave][0];        // wave-uniform slab bases
  bf16_t* ldsA1 = &sA[64 + 16 * wave][0];
  bf16_t* ldsB0 = &sB[16 * wave][0];
  bf16_t* ldsB1 = &sB[64 + 16 * wave][0];

  for (int k0 = 0; k0 < K; k0 += 32) {
    __syncthreads();                        // prev-iter frag reads done
    gload_lds16(Ag0 + k0, ldsA0);
    gload_lds16(Ag1 + k0, ldsA1);
    gload_lds16(Bg0 + k0, ldsB0);
    gload_lds16(Bg1 + k0, ldsB1);
    __syncthreads();                        // vmcnt(0) drain -> data visible
    bf16x8 afr[4], bfr[4];
#pragma unroll
    for (int i = 0; i < 4; i++) {
      afr[i] = *(const bf16x8*)(&sA[wm + i * 16 + fm][kq * 8]);
      bfr[i] = *(const bf16x8*)(&sB[wn + i * 16 + fm][kq * 8]);
    }
#pragma unroll
    for (int mi = 0; mi < 4; mi++)
#pragma unroll
      for (int ni = 0; ni < 4; ni++)
        acc[mi][ni] = __builtin_amdgcn_mfma_f32_16x16x32_bf16(afr[mi], bfr[ni], acc[mi][ni], 0, 0, 0);
  }

  const int rr = (lane >> 4) * 4;
#pragma unroll
  for (int mi = 0; mi < 4; mi++) {
#pragma unroll
    for (int r = 0; r < 4; r++) {
      const int row = bm0 + wm + mi * 16 + rr + r;
#pragma unroll
      for (int ni = 0; ni < 4; ni++) {
        const int col = bn0 + wn + ni * 16 + fm;
        if constexpr (OUT_BF16)
          ((bf16_t*)Cv)[(size_t)row * ldc + col] = (bf16_t)acc[mi][ni][r];
        else
          ((float*)Cv)[(size_t)row * ldc + col] = acc[mi][ni][r];
      }
    }
  }
}

// ---------------- conv + silu (+ l2norm) : raw bf16 [T,CH] -> out bf16 [T,CH] ----------------
template<bool L2NORM>
__global__ __launch_bounds__(256) void conv_silu(
    const bf16_t* __restrict__ raw, const float* __restrict__ wconv,
    bf16_t* __restrict__ out) {
  const int t   = blockIdx.x;
  const int tid = threadIdx.x;
  const int c0  = tid * 8;

  float w[8][4];
#pragma unroll
  for (int j = 0; j < 8; j++) {
    float4 t0 = *(const float4*)(wconv + (size_t)(c0 + j) * 4);
    w[j][0] = t0.x; w[j][1] = t0.y; w[j][2] = t0.z; w[j][3] = t0.w;
  }
  float a[8] = {};
#pragma unroll
  for (int i = 0; i < 4; i++) {
    int tr = t - 3 + i;
    if (tr < 0) continue;
    bf16x8 xr = *(const bf16x8*)(raw + (size_t)tr * CH + c0);
#pragma unroll
    for (int j = 0; j < 8; j++) a[j] += w[j][i] * (float)xr[j];
  }
  float s = 0.f;
#pragma unroll
  for (int j = 0; j < 8; j++) {
    a[j] = a[j] / (1.f + expf(-a[j]));  // silu
    s += a[j] * a[j];
  }
  float rs = 1.f;
  if constexpr (L2NORM) {
#pragma unroll
    for (int m = 1; m < 16; m <<= 1) s += __shfl_xor(s, m);
    rs = rsqrtf(s + 1e-6f);
  }
  bf16x8 r;
#pragma unroll
  for (int j = 0; j < 8; j++) r[j] = (bf16_t)(a[j] * rs);
  *(bf16x8*)(out + (size_t)t * CH + c0) = r;
}

// ---------------- gamma: writes g = -a*softplus (LOG decay) + beta sigmoid ----------------
__global__ __launch_bounds__(256) void gamma_beta(
    float* __restrict__ f_gam, const float* __restrict__ dt_bias,
    const float* __restrict__ A_log, float* __restrict__ beta_io) {
  const int t   = blockIdx.x;
  const int tid = threadIdx.x;
  const int c0  = tid * 8;
  const int h   = c0 >> 7;
  const float a_h = expf(A_log[h]);
  const size_t o0 = (size_t)t * CH + c0;
  float fv[8], db[8];
  { float4 f0 = *(const float4*)(f_gam + o0);   float4 f1 = *(const float4*)(f_gam + o0 + 4);
    fv[0]=f0.x; fv[1]=f0.y; fv[2]=f0.z; fv[3]=f0.w; fv[4]=f1.x; fv[5]=f1.y; fv[6]=f1.z; fv[7]=f1.w;
    float4 d0 = *(const float4*)(dt_bias + c0); float4 d1 = *(const float4*)(dt_bias + c0 + 4);
    db[0]=d0.x; db[1]=d0.y; db[2]=d0.z; db[3]=d0.w; db[4]=d1.x; db[5]=d1.y; db[6]=d1.z; db[7]=d1.w; }
  float og[8];
#pragma unroll
  for (int j = 0; j < 8; j++) {
    float f = fv[j] + db[j];
    float sp = (f > 20.f) ? f : log1pf(expf(f));
    og[j] = -a_h * sp;                       // g (log-decay), exp applied in prep
  }
  *(float4*)(f_gam + o0)     = make_float4(og[0], og[1], og[2], og[3]);
  *(float4*)(f_gam + o0 + 4) = make_float4(og[4], og[5], og[6], og[7]);
  if (tid < NH) {
    float b = beta_io[(size_t)t * NH + tid];
    beta_io[(size_t)t * NH + tid] = 1.f / (1.f + expf(-b));
  }
}

// ---------------- helpers for WY kernels ----------------
template<int IMM>
__device__ __forceinline__ float swzf(float x) {
  return __builtin_bit_cast(float, __builtin_amdgcn_ds_swizzle(__builtin_bit_cast(int, x), IMM));
}
template<int CTRL>
__device__ __forceinline__ float dppadd(float x) {
  int v = __builtin_amdgcn_update_dpp(0, __builtin_bit_cast(int, x), CTRL, 0xF, 0xF, true);
  return x + __builtin_bit_cast(float, v);
}
__device__ __forceinline__ float cumsum16(float x) {  // inclusive scan within 16-lane row
  x = dppadd<0x111>(x);  // row_shr:1
  x = dppadd<0x112>(x);  // row_shr:2
  x = dppadd<0x114>(x);  // row_shr:4
  x = dppadd<0x118>(x);  // row_shr:8
  return x;
}
__device__ __forceinline__ float bperm(int lane, float x) {
  return __builtin_bit_cast(float, __builtin_amdgcn_ds_bpermute(lane << 2, __builtin_bit_cast(int, x)));
}
__device__ __forceinline__ floatx2 bfpair(unsigned u) {
  floatx2 r;
  r[0] = __builtin_bit_cast(float, u << 16);
  r[1] = __builtin_bit_cast(float, u & 0xFFFF0000u);
  return r;
}

// ---------------- WY prep: fully parallel over (head, chunk) ----------------
__global__ __launch_bounds__(64) void wy_prep(
    bf16_t* __restrict__ qn, bf16_t* __restrict__ kn,
    const float* __restrict__ gg, const float* __restrict__ beta,
    bf16_t* __restrict__ ktilT, float* __restrict__ Tm,
    bf16_t* __restrict__ MBf, float* __restrict__ ecT, float* __restrict__ e2T) {
  const int hc = blockIdx.x;        // h*NCH + c
  const int h  = hc >> 8;           // NCH = 256
  const int c  = hc & 255;
  const int l  = threadIdx.x;
  const int tl = l & 15;            // t within chunk
  const int gr = l >> 4;            // 0..3

  __shared__ bf16_t KldsT[128][24];  // ktil^T [k][t], 48B rows (16B-aligned)
  __shared__ float  Wlds[16][17];    // W[t][s]
  __shared__ float  Mlds[16][17];    // masked M[t][s]
  __shared__ float  eclds[128], e2lds[128];
  __shared__ float  blds[16];

  const int kb0 = h * DH + gr * 8;
  const size_t rowoff = (size_t)(c * CHUNK + tl) * CH;

  if (gr == 0) blds[tl] = beta[(size_t)(c * CHUNK + tl) * NH + h];

  floatx4 wt = (floatx4){0.f, 0.f, 0.f, 0.f};
  floatx4 m  = (floatx4){0.f, 0.f, 0.f, 0.f};
  bf16x8 khs[4], qhs[4];
#pragma unroll
  for (int kb = 0; kb < 4; kb++) {
    const int ke = kb0 + kb * 32;
    float4 ga = *(const float4*)(gg + rowoff + ke);
    float4 gb = *(const float4*)(gg + rowoff + ke + 4);
    float cm[8] = {ga.x, ga.y, ga.z, ga.w, gb.x, gb.y, gb.z, gb.w};
    float lamh[8], lamt[8], ec[8], e2[8];
#pragma unroll
    for (int j = 0; j < 8; j++) {
      float cs   = cumsum16(cm[j]);                 // inclusive cumg over t
      float cmid = swzf<(7 << 5) | 0x10>(cs);       // c = cumg at t=7
      lamh[j] = __expf(cs - cmid);
      lamt[j] = __expf(cmid - cs);
      ec[j]   = __expf(cmid);
      e2[j]   = swzf<(15 << 5) | 0x10>(lamh[j]);    // exp(cumg15 - c)
    }
    if (tl == 0) {
#pragma unroll
      for (int j = 0; j < 8; j++) {
        eclds[kb * 32 + gr * 8 + j] = ec[j];
        e2lds[kb * 32 + gr * 8 + j] = e2[j];
      }
    }
    uint4 kr = *(const uint4*)(kn + rowoff + ke);
    uint4 qr = *(const uint4*)(qn + rowoff + ke);
    float kf[8], qf[8];
    { floatx2 a0 = bfpair(kr.x), a1 = bfpair(kr.y), a2 = bfpair(kr.z), a3 = bfpair(kr.w);
      kf[0]=a0[0];kf[1]=a0[1];kf[2]=a1[0];kf[3]=a1[1];kf[4]=a2[0];kf[5]=a2[1];kf[6]=a3[0];kf[7]=a3[1];
      floatx2 b0 = bfpair(qr.x), b1 = bfpair(qr.y), b2 = bfpair(qr.z), b3 = bfpair(qr.w);
      qf[0]=b0[0];qf[1]=b0[1];qf[2]=b1[0];qf[3]=b1[1];qf[4]=b2[0];qf[5]=b2[1];qf[6]=b3[0];qf[7]=b3[1]; }
    bf16x8 khat, ktil, qhat;
#pragma unroll
    for (int j = 0; j < 8; j++) {
      khat[j] = (bf16_t)(kf[j] * lamh[j]);
      ktil[j] = (bf16_t)(kf[j] * lamt[j]);
      qhat[j] = (bf16_t)(qf[j] * lamh[j]);
      khs[kb][j] = (bf16_t)(kf[j] * lamh[j] * ec[j]);   // k * exp(cumg)
      qhs[kb][j] = (bf16_t)(qf[j] * lamh[j] * ec[j]);
    }
    wt = __builtin_amdgcn_mfma_f32_16x16x32_bf16(ktil, khat, wt, 0, 0, 0);  // W^T
    m  = __builtin_amdgcn_mfma_f32_16x16x32_bf16(qhat, ktil, m,  0, 0, 0);  // M
#pragma unroll
    for (int j = 0; j < 8; j++) KldsT[kb * 32 + gr * 8 + j][tl] = ktil[j];
  }
  // in-place khs/qhs stores (all reads of this slice completed above)
#pragma unroll
  for (int kb = 0; kb < 4; kb++) {
    *(uint4*)(kn + rowoff + kb0 + kb * 32) = __builtin_bit_cast(uint4, khs[kb]);
    *(uint4*)(qn + rowoff + kb0 + kb * 32) = __builtin_bit_cast(uint4, qhs[kb]);
  }
  // W, masked M to LDS
#pragma unroll
  for (int ri = 0; ri < 4; ri++) {
    Wlds[tl][4 * gr + ri] = wt[ri];                               // W[t=tl][s=4gr+ri]
    Mlds[4 * gr + ri][tl] = (4 * gr + ri >= tl) ? m[ri] : 0.f;    // M[t][s], tril incl
  }
  // T solve (exact f32): X = inv(I + tril_strict(diag(b)W)); T[t][j] = X[t][j]*b_j
  {
    const int j = tl;
    float x[16];
#pragma unroll
    for (int t = 0; t < 16; t++) {
      float a = 0.f;
#pragma unroll
      for (int s = 0; s < 16; s++)
        if (s < t) a = fmaf(Wlds[t][s], x[s], a);
      x[t] = (t == j) ? 1.f : ((t > j) ? -blds[t] * a : 0.f);
    }
    if (gr == 0) {
      const float bj = blds[j];
#pragma unroll
      for (int t = 0; t < 16; t++)
        Tm[((size_t)hc * 16 + t) * 16 + j] = x[t] * bj;
    }
  }
  // masked-M as ready B-frag (col=t=tl, elems s=gr*8+jj; gr>=2 zero)
  {
    uint4 mbo = {0, 0, 0, 0};
    if (gr < 2) {
      bf16x8 mm;
#pragma unroll
      for (int jj = 0; jj < 8; jj++) mm[jj] = (bf16_t)Mlds[tl][gr * 8 + jj];
      mbo = __builtin_bit_cast(uint4, mm);
    }
    ((uint4*)MBf)[(size_t)hc * 64 + l] = mbo;
  }
  // ktil^T -> global (coalesced rows of 16 bf16)
  for (int i = l; i < 128; i += 64) {
    uint4 a0 = *(const uint4*)&KldsT[i][0];
    uint4 a1 = *(const uint4*)&KldsT[i][8];
    bf16_t* dst = ktilT + ((size_t)hc * 128 + i) * 16;
    *(uint4*)dst = a0;
    *(uint4*)(dst + 8) = a1;
  }
  // ec/e2 transposed for float4 loads: [tl][kt]
  for (int i = l; i < 128; i += 64) {
    ecT[(size_t)hc * 128 + (i & 15) * 8 + (i >> 4)] = eclds[i];
    e2T[(size_t)hc * 128 + (i & 15) * 8 + (i >> 4)] = e2lds[i];
  }
}

// ---------------- serial WY scan, wave-specialized producer/consumer ----------------
// Round-9 change: DV solve no longer uses 64 ds_bpermutes (DS-pipe hog, ~500cy
// + contention with producer ds_writes). Instead: write V' once to DVlds, then
// 16 broadcast ds_read_b128 (all 16 tl-lanes same address -> no conflict),
// exact f32 FMA into dv. DS ops in solve: 73 -> ~26.
__global__ __launch_bounds__(128, 1) void scan_wy3(
    const bf16_t* __restrict__ khsG, const bf16_t* __restrict__ qhsG,
    const bf16_t* __restrict__ vn, const bf16_t* __restrict__ ktilT,
    const float* __restrict__ Tm, const bf16_t* __restrict__ MBf,
    const float* __restrict__ ecT, const float* __restrict__ e2T,
    float* __restrict__ o) {
  const int h   = blockIdx.x >> 3;   // 16 heads
  const int vt  = blockIdx.x & 7;    // 8 v-tiles
  const int tid = threadIdx.x;
  const int wid = tid >> 6;          // 0 = consumer, 1 = producer
  const int l   = tid & 63;
  const int tl  = l & 15;
  const int gr  = l >> 4;

  __shared__ uint4   sKQ[2][8][64];   // khs kb0..3, qhs kb0..3  (16 KiB)
  __shared__ floatx4 sT[2][4][64];    // T rows                   (8 KiB)
  __shared__ uint4   sMB[2][64];      // masked-M B-frag          (2 KiB)
  __shared__ uint4   sKT[2][8][64];   // ktil B-frags             (16 KiB)
  __shared__ floatx4 sEC[2][4][64];   // ec0,ec1,e20,e21          (8 KiB)
  __shared__ uint2   sV[2][64];       // v                        (1 KiB)
  __shared__ float   SldsT[16][132];  // S^T [v][k]               (8.25 KiB)
  __shared__ float   DVlds[16][17];   // V' then dv [t][v]

  const int kb0 = h * DH + gr * 8;
  const int vb0 = h * DH + vt * 16 + gr * 4;
  const size_t hcBase = (size_t)h * NCH;
  constexpr float scale = 0.08838834764831845f;

  auto produce = [&](int c, int b) {
    const size_t rowoff = (size_t)(c * CHUNK + tl) * CH;
    const size_t hc = hcBase + c;
    uint4 kq[8];
#pragma unroll
    for (int kb = 0; kb < 4; kb++) {
      kq[kb]     = *(const uint4*)(khsG + rowoff + kb0 + kb * 32);
      kq[4 + kb] = *(const uint4*)(qhsG + rowoff + kb0 + kb * 32);
    }
    const float* Trp = Tm + (hc * 16 + tl) * 16;
    floatx4 Tv[4];
#pragma unroll
    for (int j = 0; j < 4; j++) Tv[j] = *(const floatx4*)(Trp + 4 * j);
    uint4 mbv = ((const uint4*)MBf)[hc * 64 + l];
    const int g2 = gr & 1;
    uint4 ktv[8];
#pragma unroll
    for (int kt = 0; kt < 8; kt++)
      ktv[kt] = *(const uint4*)(ktilT + (hc * 128 + kt * 16 + tl) * 16 + g2 * 8);
    floatx4 ecv[4];
    ecv[0] = *(const floatx4*)(ecT + hc * 128 + tl * 8);
    ecv[1] = *(const floatx4*)(ecT + hc * 128 + tl * 8 + 4);
    ecv[2] = *(const floatx4*)(e2T + hc * 128 + tl * 8);
    ecv[3] = *(const floatx4*)(e2T + hc * 128 + tl * 8 + 4);
    uint2 vv = *(const uint2*)(vn + rowoff + vb0);
#pragma unroll
    for (int i = 0; i < 8; i++) sKQ[b][i][l] = kq[i];
#pragma unroll
    for (int j = 0; j < 4; j++) sT[b][j][l] = Tv[j];
    sMB[b][l] = mbv;
#pragma unroll
    for (int i = 0; i < 8; i++) sKT[b][i][l] = ktv[i];
#pragma unroll
    for (int j = 0; j < 4; j++) sEC[b][j][l] = ecv[j];
    sV[b][l] = vv;
  };

  float S[8][4];
#pragma unroll
  for (int kt = 0; kt < 8; kt++)
#pragma unroll
    for (int ri = 0; ri < 4; ri++) S[kt][ri] = 0.f;

  if (wid == 1) {
    produce(0, 0);
  } else {
    for (int i = l; i < 16 * 132; i += 64) (&SldsT[0][0])[i] = 0.f;
  }
  __syncthreads();

  int cur = 0;
  for (int c = 0; c < NCH; ++c) {
    if (wid == 1) {
      produce(c + 1 < NCH ? c + 1 : NCH - 1, cur ^ 1);
    } else {
      const size_t rowoff = (size_t)(c * CHUNK + tl) * CH;
      // ---- P, O1 from S0 ----
      floatx4 p  = (floatx4){0.f, 0.f, 0.f, 0.f};
      floatx4 o1 = (floatx4){0.f, 0.f, 0.f, 0.f};
#pragma unroll
      for (int kb = 0; kb < 4; kb++) {
        float4 sa = *(const float4*)(&SldsT[tl][kb * 32 + gr * 8]);
        float4 sb = *(const float4*)(&SldsT[tl][kb * 32 + gr * 8 + 4]);
        bf16x8 s0a;
        s0a[0]=(bf16_t)sa.x; s0a[1]=(bf16_t)sa.y; s0a[2]=(bf16_t)sa.z; s0a[3]=(bf16_t)sa.w;
        s0a[4]=(bf16_t)sb.x; s0a[5]=(bf16_t)sb.y; s0a[6]=(bf16_t)sb.z; s0a[7]=(bf16_t)sb.w;
        p  = __builtin_amdgcn_mfma_f32_16x16x32_bf16(s0a, __builtin_bit_cast(bf16x8, sKQ[cur][kb][l]), p,  0, 0, 0);
        o1 = __builtin_amdgcn_mfma_f32_16x16x32_bf16(s0a, __builtin_bit_cast(bf16x8, sKQ[cur][4 + kb][l]), o1, 0, 0, 0);
      }
      // ---- V' = V - P -> DVlds; DV = T*V' via broadcast LDS reads (exact f32) ----
      float acc[4];
      { uint2 vr = sV[cur][l];
        floatx2 v01 = bfpair(vr.x), v23 = bfpair(vr.y);
        acc[0] = v01[0] - p[0]; acc[1] = v01[1] - p[1];
        acc[2] = v23[0] - p[2]; acc[3] = v23[1] - p[3]; }
      *(float4*)(&DVlds[tl][4 * gr]) = make_float4(acc[0], acc[1], acc[2], acc[3]);
      floatx4 T0 = sT[cur][0][l], T1 = sT[cur][1][l], T2 = sT[cur][2][l], T3 = sT[cur][3][l];
      float dv[4] = {0.f, 0.f, 0.f, 0.f};
#pragma unroll
      for (int s = 0; s < 16; s++) {
        const float ts = (s < 4) ? T0[s] : (s < 8) ? T1[s - 4] : (s < 12) ? T2[s - 8] : T3[s - 12];
        float4 vp = *(const float4*)(&DVlds[s][4 * gr]);   // 16 tl-lanes same addr: broadcast
        dv[0] = fmaf(ts, vp.x, dv[0]);
        dv[1] = fmaf(ts, vp.y, dv[1]);
        dv[2] = fmaf(ts, vp.z, dv[2]);
        dv[3] = fmaf(ts, vp.w, dv[3]);
      }
#pragma unroll
      for (int ri = 0; ri < 4; ri++) DVlds[tl][4 * gr + ri] = dv[ri];
      bf16x8 dva = {};
      if (gr < 2) {
#pragma unroll
        for (int jj = 0; jj < 8; jj++) dva[jj] = (bf16_t)DVlds[gr * 8 + jj][tl];
      }
      // ---- O2, store O ----
      floatx4 o2 = __builtin_amdgcn_mfma_f32_16x16x32_bf16(
          dva, __builtin_bit_cast(bf16x8, sMB[cur][l]), (floatx4){0.f, 0.f, 0.f, 0.f}, 0, 0, 0);
      { float4 ov = make_float4((o1[0] + o2[0]) * scale, (o1[1] + o2[1]) * scale,
                                (o1[2] + o2[2]) * scale, (o1[3] + o2[3]) * scale);
        *(float4*)(o + rowoff + vb0) = ov; }
      // ---- S update: S' = e2*(ec*S0 + DV^T K~) ----
      floatx4 ec0 = sEC[cur][0][l], ec1 = sEC[cur][1][l];
      floatx4 e20 = sEC[cur][2][l], e21 = sEC[cur][3][l];
#pragma unroll
      for (int kt = 0; kt < 8; kt++) {
        const float ecK = (kt < 4) ? ec0[kt] : ec1[kt - 4];
        const float e2K = (kt < 4) ? e20[kt] : e21[kt - 4];
        floatx4 sa;
#pragma unroll
        for (int ri = 0; ri < 4; ri++) sa[ri] = ecK * S[kt][ri];
        sa = __builtin_amdgcn_mfma_f32_16x16x32_bf16(
            dva, __builtin_bit_cast(bf16x8, sKT[cur][kt][l]), sa, 0, 0, 0);
#pragma unroll
        for (int ri = 0; ri < 4; ri++) S[kt][ri] = e2K * sa[ri];
      }
      // ---- publish S^T for next chunk ----
#pragma unroll
      for (int kt = 0; kt < 8; kt++)
#pragma unroll
        for (int ri = 0; ri < 4; ri++)
          SldsT[4 * gr + ri][kt * 16 + tl] = S[kt][ri];
    }
    __syncthreads();
    cur ^= 1;
  }
}

// ---------------- postprocess: RMSNorm * norm_w * silu(gate bf16) -> bf16 ----------------
__global__ __launch_bounds__(256) void postprocess(
    const float* __restrict__ o, const bf16_t* __restrict__ gate,
    const float* __restrict__ norm_w, bf16_t* __restrict__ og) {
  const int t = blockIdx.x, tid = threadIdx.x;
  const int c0 = tid * 8, d0 = c0 & 127;
  const size_t o0 = (size_t)t * CH + c0;
  float ov[8], gv[8], nw[8];
  { float4 a = *(const float4*)(o + o0);    float4 b = *(const float4*)(o + o0 + 4);
    ov[0]=a.x; ov[1]=a.y; ov[2]=a.z; ov[3]=a.w; ov[4]=b.x; ov[5]=b.y; ov[6]=b.z; ov[7]=b.w;
    bf16x8 g8 = *(const bf16x8*)(gate + o0);
    for (int j = 0; j < 8; j++) gv[j] = (float)g8[j];
    float4 e = *(const float4*)(norm_w + d0); float4 f = *(const float4*)(norm_w + d0 + 4);
    nw[0]=e.x; nw[1]=e.y; nw[2]=e.z; nw[3]=e.w; nw[4]=f.x; nw[5]=f.y; nw[6]=f.z; nw[7]=f.w; }
  float ss = 0.f;
#pragma unroll
  for (int j = 0; j < 8; j++) ss += ov[j] * ov[j];
#pragma unroll
  for (int m = 1; m < 16; m <<= 1) ss += __shfl_xor(ss, m);
  const float rs = rsqrtf(ss * (1.f / 128.f) + 1e-6f);
  bf16x8 r;
#pragma unroll
  for (int j = 0; j < 8; j++) {
    float g = gv[j];
    float val = ov[j] * rs * nw[j] * (g / (1.f + expf(-g)));
    r[j] = (bf16_t)val;
  }
  *(bf16x8*)(og + o0) = r;
}

// ---------------- host launcher ----------------
static inline void launch_gemm(const bf16_t* A, int lda, const bf16_t* Bt, int ldb,
                               void* C, int ldc, int M, int N, int K, bool obf16,
                               hipStream_t s) {
  dim3 grid(M / 128, (N + 127) / 128);
  if ((N & 127) == 0) {
    if (obf16) gemm_bf16_lds<true><<<grid, 256, 0, s>>>(A, lda, Bt, ldb, C, ldc, M, N, K);
    else       gemm_bf16_lds<false><<<grid, 256, 0, s>>>(A, lda, Bt, ldb, C, ldc, M, N, K);
  } else {
    if (obf16) gemm_bf16<true><<<grid, 256, 0, s>>>(A, lda, Bt, ldb, C, ldc, M, N, K);
    else       gemm_bf16<false><<<grid, 256, 0, s>>>(A, lda, Bt, ldb, C, ldc, M, N, K);
  }
}

extern "C" void kernel_launch(void* const* d_in, const int* in_sizes, int n_in,
                              void* d_out, int out_size, void* d_ws, size_t ws_size,
                              hipStream_t stream) {
  const float* x       = (const float*)d_in[0];
  const float* Wq      = (const float*)d_in[1];
  const float* Wk      = (const float*)d_in[2];
  const float* Wv      = (const float*)d_in[3];
  const float* wqc     = (const float*)d_in[4];
  const float* wkc     = (const float*)d_in[5];
  const float* wvc     = (const float*)d_in[6];
  const float* A_log   = (const float*)d_in[7];
  const float* dt_bias = (const float*)d_in[8];
  const float* Wfa     = (const float*)d_in[9];
  const float* Wfb     = (const float*)d_in[10];
  const float* Wb      = (const float*)d_in[11];
  const float* Wga     = (const float*)d_in[12];
  const float* Wgb     = (const float*)d_in[13];
  const float* norm_w  = (const float*)d_in[14];
  const float* Wo      = (const float*)d_in[15];

  char* w = (char*)d_ws;
  size_t off = 0;
  auto give = [&](size_t bytes) -> void* {
    size_t cur = off;
    off = (off + bytes + 255) & ~(size_t)255;
    return (void*)(w + cur);
  };
  bf16_t* Wbig = (bf16_t*)give((size_t)CH * HID * 2);   // reused: WqT,WkT,WvT,WoT
  bf16_t* WfaT = (bf16_t*)give((size_t)128 * HID * 2);
  bf16_t* WgaT = (bf16_t*)give((size_t)128 * HID * 2);
  bf16_t* WfbT = (bf16_t*)give((size_t)CH * 128 * 2);
  bf16_t* WgbT = (bf16_t*)give((size_t)CH * 128 * 2);
  bf16_t* WbT  = (bf16_t*)give((size_t)NH * HID * 2);
  bf16_t* Ax   = (bf16_t*)give((size_t)T_TOK * HID * 2);  // 16 MiB
  bf16_t* raw0 = (bf16_t*)give((size_t)T_TOK * CH * 2);   // 16 MiB, reused q/k/v raw
  bf16_t* qnb  = (bf16_t*)give((size_t)T_TOK * CH * 2);
  bf16_t* knb  = (bf16_t*)give((size_t)T_TOK * CH * 2);
  bf16_t* vnb  = (bf16_t*)give((size_t)T_TOK * CH * 2);
  bf16_t* f1b  = (bf16_t*)give((size_t)T_TOK * 128 * 2);
  bf16_t* g1b  = (bf16_t*)give((size_t)T_TOK * 128 * 2);
  float*  fbuf = (float*)give((size_t)T_TOK * CH * 4);    // f_pre -> g (log decay) in-place
  bf16_t* gateb= (bf16_t*)give((size_t)T_TOK * CH * 2);
  float*  betab= (float*)give((size_t)T_TOK * NH * 4);
  // WY precompute buffers (+28 MiB)
  bf16_t* ktilT= (bf16_t*)give((size_t)NH * NCH * 128 * 16 * 2);  // 16 MiB
  float*  Tmat = (float*)give((size_t)NH * NCH * 256 * 4);        // 4 MiB
  bf16_t* MBf  = (bf16_t*)give((size_t)NH * NCH * 64 * 8 * 2);    // 4 MiB
  float*  ecTb = (float*)give((size_t)NH * NCH * 128 * 4);        // 2 MiB
  float*  e2Tb = (float*)give((size_t)NH * NCH * 128 * 4);        // 2 MiB
  // aliases over dead regions:
  float*  obuf = (float*)Ax;    // 32 MiB = Ax(16)+raw0(16), both dead before scan
  bf16_t* ogb  = qnb;           // qnb dead after scan

  auto tr = [&](const float* in, bf16_t* out, int R, int C) {
    transpose_cast<<<dim3((R + 31) / 32, (C + 31) / 32), 256, 0, stream>>>(in, out, R, C);
  };

  // 1) cast x, small weight transposes
  cast_to_bf16<<<dim3((T_TOK * HID) / 2048), 256, 0, stream>>>(x, Ax, T_TOK * HID);
  tr(Wfa, WfaT, HID, 128); tr(Wga, WgaT, HID, 128);
  tr(Wfb, WfbT, 128, CH);  tr(Wgb, WgbT, 128, CH);
  tr(Wb, WbT, HID, NH);

  // 2) q/k/v: transpose weight -> GEMM -> conv+silu(+l2norm), reusing Wbig and raw0
  tr(Wq, Wbig, HID, CH);
  launch_gemm(Ax, HID, Wbig, HID, raw0, CH, T_TOK, CH, HID, true, stream);
  conv_silu<true><<<dim3(T_TOK), 256, 0, stream>>>(raw0, wqc, qnb);
  tr(Wk, Wbig, HID, CH);
  launch_gemm(Ax, HID, Wbig, HID, raw0, CH, T_TOK, CH, HID, true, stream);
  conv_silu<true><<<dim3(T_TOK), 256, 0, stream>>>(raw0, wkc, knb);
  tr(Wv, Wbig, HID, CH);
  launch_gemm(Ax, HID, Wbig, HID, raw0, CH, T_TOK, CH, HID, true, stream);
  conv_silu<false><<<dim3(T_TOK), 256, 0, stream>>>(raw0, wvc, vnb);

  // 3) f/g/beta chains
  launch_gemm(Ax, HID, WfaT, HID, f1b, 128, T_TOK, 128, HID, true, stream);
  launch_gemm(Ax, HID, WgaT, HID, g1b, 128, T_TOK, 128, HID, true, stream);
  launch_gemm(Ax, HID, WbT, HID, betab, NH, T_TOK, NH, HID, false, stream);
  launch_gemm(f1b, 128, WfbT, 128, fbuf, CH, T_TOK, CH, 128, false, stream);
  launch_gemm(g1b, 128, WgbT, 128, gateb, CH, T_TOK, CH, 128, true, stream);
  gamma_beta<<<dim3(T_TOK), 256, 0, stream>>>(fbuf, dt_bias, A_log, betab);

  // 4a) parallel WY prep: 4096 blocks (head x chunk)
  wy_prep<<<dim3(NH * NCH), 64, 0, stream>>>(qnb, knb, fbuf, betab,
                                             ktilT, Tmat, MBf, ecTb, e2Tb);
  // 4b) serial WY scan: 128 blocks (head x v-tile) x 2 waves (compute + producer)
  scan_wy3<<<dim3(128), 128, 0, stream>>>(knb, qnb, vnb, ktilT, Tmat, MBf,
                                          ecTb, e2Tb, obuf);

  // 5) gated RMSNorm -> bf16 (ogb aliases qnb)
  postprocess<<<dim3(T_TOK), 256, 0, stream>>>(obuf, gateb, norm_w, ogb);

  // 6) output projection
  tr(Wo, Wbig, CH, HID);
  launch_gemm(ogb, CH, Wbig, CH, (float*)d_out, HID, T_TOK, HID, CH, false, stream);
}

// Round 11
// 958.245 us; speedup vs baseline: 2.1134x; 1.0698x over previous
//
#include <hip/hip_runtime.h>
#include <hip/hip_bf16.h>
#include <math.h>

typedef __bf16 bf16_t;
typedef __bf16 bf16x8 __attribute__((ext_vector_type(8)));
typedef float  floatx4 __attribute__((ext_vector_type(4)));
typedef float  floatx2 __attribute__((ext_vector_type(2)));
typedef unsigned uintx4 __attribute__((ext_vector_type(4)));

constexpr int T_TOK = 4096;
constexpr int HID   = 2048;
constexpr int NH    = 16;
constexpr int DH    = 128;   // head dim
constexpr int CH    = 2048;  // NH*DH
constexpr int CHUNK = 16;
constexpr int NCH   = T_TOK / CHUNK;   // 256

// ---------------- cast fp32 -> bf16 (row-major preserved) ----------------
__global__ __launch_bounds__(256) void cast_to_bf16(const float* __restrict__ in,
                                                    bf16_t* __restrict__ out, int n) {
  int i = (blockIdx.x * 256 + threadIdx.x) * 8;
  if (i >= n) return;
  float4 a = *(const float4*)(in + i);
  float4 b = *(const float4*)(in + i + 4);
  bf16x8 o;
  o[0]=(bf16_t)a.x; o[1]=(bf16_t)a.y; o[2]=(bf16_t)a.z; o[3]=(bf16_t)a.w;
  o[4]=(bf16_t)b.x; o[5]=(bf16_t)b.y; o[6]=(bf16_t)b.z; o[7]=(bf16_t)b.w;
  *(bf16x8*)(out + i) = o;
}

// ---------------- transpose + cast: in fp32 [R,C] -> out bf16 [C,R] ----------------
__global__ __launch_bounds__(256) void transpose_cast(const float* __restrict__ in,
                                                      bf16_t* __restrict__ out, int R, int C) {
  __shared__ float tile[32][33];
  int tx = threadIdx.x & 31;
  int ty = threadIdx.x >> 5;  // 0..7
  int r0 = blockIdx.x * 32;
  int c0 = blockIdx.y * 32;
#pragma unroll
  for (int i = 0; i < 4; i++) {
    int r = ty + i * 8;
    float v = 0.f;
    if (r0 + r < R && c0 + tx < C) v = in[(size_t)(r0 + r) * C + (c0 + tx)];
    tile[r][tx] = v;
  }
  __syncthreads();
#pragma unroll
  for (int i = 0; i < 4; i++) {
    int cr = ty + i * 8;
    if (c0 + cr < C && r0 + tx < R)
      out[(size_t)(c0 + cr) * R + (r0 + tx)] = (bf16_t)tile[tx][cr];
  }
}

// ---------------- bf16 MFMA GEMM (general, bounds-checked): C = A * Bt^T ----------------
template<bool OUT_BF16>
__global__ __launch_bounds__(256) void gemm_bf16(
    const bf16_t* __restrict__ A, int lda,
    const bf16_t* __restrict__ Bt, int ldb,
    void* __restrict__ Cv, int ldc, int M, int N, int K) {
  __shared__ bf16_t sA[128][40];
  __shared__ bf16_t sB[128][40];
  const int tid  = threadIdx.x;
  const int bm0  = blockIdx.x * 128;
  const int bn0  = blockIdx.y * 128;
  const int wave = tid >> 6;
  const int lane = tid & 63;
  const int wm   = (wave & 1) * 64;
  const int wn   = (wave >> 1) * 64;
  const int fm   = lane & 15;
  const int kq   = lane >> 4;

  floatx4 acc[4][4];
#pragma unroll
  for (int mi = 0; mi < 4; mi++)
#pragma unroll
    for (int ni = 0; ni < 4; ni++)
      acc[mi][ni] = (floatx4){0.f, 0.f, 0.f, 0.f};

  const int sr = tid >> 2;
  const int sk = (tid & 3) * 8;
  const bool bval0 = (bn0 + sr) < N;
  const bool bval1 = (bn0 + sr + 64) < N;
  const bf16_t* Ag0 = A + (size_t)(bm0 + sr) * lda + sk;
  const bf16_t* Ag1 = Ag0 + (size_t)64 * lda;
  const bf16_t* Bg0 = Bt + (size_t)(bn0 + sr) * ldb + sk;
  const bf16_t* Bg1 = Bg0 + (size_t)64 * ldb;

  for (int k0 = 0; k0 < K; k0 += 32) {
    float4 a0 = *(const float4*)(Ag0 + k0);
    float4 a1 = *(const float4*)(Ag1 + k0);
    float4 b0 = bval0 ? *(const float4*)(Bg0 + k0) : make_float4(0.f, 0.f, 0.f, 0.f);
    float4 b1 = bval1 ? *(const float4*)(Bg1 + k0) : make_float4(0.f, 0.f, 0.f, 0.f);
    __syncthreads();
    *(float4*)(&sA[sr][sk])      = a0;
    *(float4*)(&sA[sr + 64][sk]) = a1;
    *(float4*)(&sB[sr][sk])      = b0;
    *(float4*)(&sB[sr + 64][sk]) = b1;
    __syncthreads();
    bf16x8 afr[4], bfr[4];
#pragma unroll
    for (int i = 0; i < 4; i++) {
      afr[i] = *(const bf16x8*)(&sA[wm + i * 16 + fm][kq * 8]);
      bfr[i] = *(const bf16x8*)(&sB[wn + i * 16 + fm][kq * 8]);
    }
#pragma unroll
    for (int mi = 0; mi < 4; mi++)
#pragma unroll
      for (int ni = 0; ni < 4; ni++)
        acc[mi][ni] = __builtin_amdgcn_mfma_f32_16x16x32_bf16(afr[mi], bfr[ni], acc[mi][ni], 0, 0, 0);
  }

  const int rr = (lane >> 4) * 4;
#pragma unroll
  for (int mi = 0; mi < 4; mi++) {
#pragma unroll
    for (int r = 0; r < 4; r++) {
      const int row = bm0 + wm + mi * 16 + rr + r;
#pragma unroll
      for (int ni = 0; ni < 4; ni++) {
        const int col = bn0 + wn + ni * 16 + fm;
        if (col < N) {
          if constexpr (OUT_BF16)
            ((bf16_t*)Cv)[(size_t)row * ldc + col] = (bf16_t)acc[mi][ni][r];
          else
            ((float*)Cv)[(size_t)row * ldc + col] = acc[mi][ni][r];
        }
      }
    }
  }
}

// ---------------- fast GEMM: 2-phase double-buffered global_load_lds ----------------
// T3-minimum structure (guide §5.5): STAGE(buf^1, k+1) issued BEFORE the
// ds_read+MFMA on buf[cur]; ONE barrier per K-step. The compiler's vmcnt(0)
// drain before s_barrier then lands AFTER ~150cy of compute, hiding most of
// the load latency (round-10's version issued loads right before the drain —
// fully exposed, 0 gain). Requires M%128==0, N%128==0, K%32==0.
__device__ __forceinline__ void gload_lds16(const bf16_t* g, bf16_t* l) {
  __builtin_amdgcn_global_load_lds(
      (const __attribute__((address_space(1))) void*)g,
      (__attribute__((address_space(3))) void*)l, 16, 0, 0);
}

template<bool OUT_BF16>
__global__ __launch_bounds__(256) void gemm_bf16_lds(
    const bf16_t* __restrict__ A, int lda,
    const bf16_t* __restrict__ Bt, int ldb,
    void* __restrict__ Cv, int ldc, int M, int N, int K) {
  __shared__ bf16_t sA[2][128][32];
  __shared__ bf16_t sB[2][128][32];
  const int tid  = threadIdx.x;
  const int bm0  = blockIdx.x * 128;
  const int bn0  = blockIdx.y * 128;
  const int wave = tid >> 6;
  const int lane = tid & 63;
  const int wm   = (wave & 1) * 64;
  const int wn   = (wave >> 1) * 64;
  const int fm   = lane & 15;
  const int kq   = lane >> 4;

  floatx4 acc[4][4];
#pragma unroll
  for (int mi = 0; mi < 4; mi++)
#pragma unroll
    for (int ni = 0; ni < 4; ni++)
      acc[mi][ni] = (floatx4){0.f, 0.f, 0.f, 0.f};

  const int sr = tid >> 2;          // 0..63
  const int sk = (tid & 3) * 8;
  const bf16_t* Ag0 = A + (size_t)(bm0 + sr) * lda + sk;
  const bf16_t* Ag1 = Ag0 + (size_t)64 * lda;
  const bf16_t* Bg0 = Bt + (size_t)(bn0 + sr) * ldb + sk;
  const bf16_t* Bg1 = Bg0 + (size_t)64 * ldb;

  auto stage = [&](int b, int k0) {
    gload_lds16(Ag0 + k0, &sA[b][16 * wave][0]);
    gload_lds16(Ag1 + k0, &sA[b][64 + 16 * wave][0]);
    gload_lds16(Bg0 + k0, &sB[b][16 * wave][0]);
    gload_lds16(Bg1 + k0, &sB[b][64 + 16 * wave][0]);
  };

  stage(0, 0);
  __syncthreads();                        // tile 0 resident
  int cur = 0;
  for (int k0 = 0; k0 < K; k0 += 32) {
    if (k0 + 32 < K) stage(cur ^ 1, k0 + 32);   // issue early: hides under MFMA
    bf16x8 afr[4], bfr[4];
#pragma unroll
    for (int i = 0; i < 4; i++) {
      afr[i] = *(const bf16x8*)(&sA[cur][wm + i * 16 + fm][kq * 8]);
      bfr[i] = *(const bf16x8*)(&sB[cur][wn + i * 16 + fm][kq * 8]);
    }
#pragma unroll
    for (int mi = 0; mi < 4; mi++)
#pragma unroll
      for (int ni = 0; ni < 4; ni++)
        acc[mi][ni] = __builtin_amdgcn_mfma_f32_16x16x32_bf16(afr[mi], bfr[ni], acc[mi][ni], 0, 0, 0);
    __syncthreads();                      // drains next-tile loads + read fence
    cur ^= 1;
  }

  const int rr = (lane >> 4) * 4;
#pragma unroll
  for (int mi = 0; mi < 4; mi++) {
#pragma unroll
    for (int r = 0; r < 4; r++) {
      const int row = bm0 + wm + mi * 16 + rr + r;
#pragma unroll
      for (int ni = 0; ni < 4; ni++) {
        const int col = bn0 + wn + ni * 16 + fm;
        if constexpr (OUT_BF16)
          ((bf16_t*)Cv)[(size_t)row * ldc + col] = (bf16_t)acc[mi][ni][r];
        else
          ((float*)Cv)[(size_t)row * ldc + col] = acc[mi][ni][r];
      }
    }
  }
}

// ---------------- conv + silu (+ l2norm) : raw bf16 [T,CH] -> out bf16 [T,CH] ----------------
template<bool L2NORM>
__global__ __launch_bounds__(256) void conv_silu(
    const bf16_t* __restrict__ raw, const float* __restrict__ wconv,
    bf16_t* __restrict__ out) {
  const int t   = blockIdx.x;
  const int tid = threadIdx.x;
  const int c0  = tid * 8;

  float w[8][4];
#pragma unroll
  for (int j = 0; j < 8; j++) {
    float4 t0 = *(const float4*)(wconv + (size_t)(c0 + j) * 4);
    w[j][0] = t0.x; w[j][1] = t0.y; w[j][2] = t0.z; w[j][3] = t0.w;
  }
  float a[8] = {};
#pragma unroll
  for (int i = 0; i < 4; i++) {
    int tr = t - 3 + i;
    if (tr < 0) continue;
    bf16x8 xr = *(const bf16x8*)(raw + (size_t)tr * CH + c0);
#pragma unroll
    for (int j = 0; j < 8; j++) a[j] += w[j][i] * (float)xr[j];
  }
  float s = 0.f;
#pragma unroll
  for (int j = 0; j < 8; j++) {
    a[j] = a[j] / (1.f + expf(-a[j]));  // silu
    s += a[j] * a[j];
  }
  float rs = 1.f;
  if constexpr (L2NORM) {
#pragma unroll
    for (int m = 1; m < 16; m <<= 1) s += __shfl_xor(s, m);
    rs = rsqrtf(s + 1e-6f);
  }
  bf16x8 r;
#pragma unroll
  for (int j = 0; j < 8; j++) r[j] = (bf16_t)(a[j] * rs);
  *(bf16x8*)(out + (size_t)t * CH + c0) = r;
}

// ---------------- gamma: writes g = -a*softplus (LOG decay) + beta sigmoid ----------------
__global__ __launch_bounds__(256) void gamma_beta(
    float* __restrict__ f_gam, const float* __restrict__ dt_bias,
    const float* __restrict__ A_log, float* __restrict__ beta_io) {
  const int t   = blockIdx.x;
  const int tid = threadIdx.x;
  const int c0  = tid * 8;
  const int h   = c0 >> 7;
  const float a_h = expf(A_log[h]);
  const size_t o0 = (size_t)t * CH + c0;
  float fv[8], db[8];
  { float4 f0 = *(const float4*)(f_gam + o0);   float4 f1 = *(const float4*)(f_gam + o0 + 4);
    fv[0]=f0.x; fv[1]=f0.y; fv[2]=f0.z; fv[3]=f0.w; fv[4]=f1.x; fv[5]=f1.y; fv[6]=f1.z; fv[7]=f1.w;
    float4 d0 = *(const float4*)(dt_bias + c0); float4 d1 = *(const float4*)(dt_bias + c0 + 4);
    db[0]=d0.x; db[1]=d0.y; db[2]=d0.z; db[3]=d0.w; db[4]=d1.x; db[5]=d1.y; db[6]=d1.z; db[7]=d1.w; }
  float og[8];
#pragma unroll
  for (int j = 0; j < 8; j++) {
    float f = fv[j] + db[j];
    float sp = (f > 20.f) ? f : log1pf(expf(f));
    og[j] = -a_h * sp;                       // g (log-decay), exp applied in prep
  }
  *(float4*)(f_gam + o0)     = make_float4(og[0], og[1], og[2], og[3]);
  *(float4*)(f_gam + o0 + 4) = make_float4(og[4], og[5], og[6], og[7]);
  if (tid < NH) {
    float b = beta_io[(size_t)t * NH + tid];
    beta_io[(size_t)t * NH + tid] = 1.f / (1.f + expf(-b));
  }
}

// ---------------- helpers for WY kernels ----------------
template<int IMM>
__device__ __forceinline__ float swzf(float x) {
  return __builtin_bit_cast(float, __builtin_amdgcn_ds_swizzle(__builtin_bit_cast(int, x), IMM));
}
template<int CTRL>
__device__ __forceinline__ float dppadd(float x) {
  int v = __builtin_amdgcn_update_dpp(0, __builtin_bit_cast(int, x), CTRL, 0xF, 0xF, true);
  return x + __builtin_bit_cast(float, v);
}
__device__ __forceinline__ float cumsum16(float x) {  // inclusive scan within 16-lane row
  x = dppadd<0x111>(x);  // row_shr:1
  x = dppadd<0x112>(x);  // row_shr:2
  x = dppadd<0x114>(x);  // row_shr:4
  x = dppadd<0x118>(x);  // row_shr:8
  return x;
}
__device__ __forceinline__ floatx2 bfpair(unsigned u) {
  floatx2 r;
  r[0] = __builtin_bit_cast(float, u << 16);
  r[1] = __builtin_bit_cast(float, u & 0xFFFF0000u);
  return r;
}

// ---------------- WY prep: fully parallel over (head, chunk) ----------------
__global__ __launch_bounds__(64) void wy_prep(
    bf16_t* __restrict__ qn, bf16_t* __restrict__ kn,
    const float* __restrict__ gg, const float* __restrict__ beta,
    bf16_t* __restrict__ ktilT, float* __restrict__ Tm,
    bf16_t* __restrict__ MBf, float* __restrict__ ecT, float* __restrict__ e2T) {
  const int hc = blockIdx.x;        // h*NCH + c
  const int h  = hc >> 8;           // NCH = 256
  const int c  = hc & 255;
  const int l  = threadIdx.x;
  const int tl = l & 15;            // t within chunk
  const int gr = l >> 4;            // 0..3

  __shared__ bf16_t KldsT[128][24];  // ktil^T [k][t], 48B rows (16B-aligned)
  __shared__ float  Wlds[16][17];    // W[t][s]
  __shared__ float  Mlds[16][17];    // masked M[t][s]
  __shared__ float  eclds[128], e2lds[128];
  __shared__ float  blds[16];

  const int kb0 = h * DH + gr * 8;
  const size_t rowoff = (size_t)(c * CHUNK + tl) * CH;

  if (gr == 0) blds[tl] = beta[(size_t)(c * CHUNK + tl) * NH + h];

  floatx4 wt = (floatx4){0.f, 0.f, 0.f, 0.f};
  floatx4 m  = (floatx4){0.f, 0.f, 0.f, 0.f};
  bf16x8 khs[4], qhs[4];
#pragma unroll
  for (int kb = 0; kb < 4; kb++) {
    const int ke = kb0 + kb * 32;
    float4 ga = *(const float4*)(gg + rowoff + ke);
    float4 gb = *(const float4*)(gg + rowoff + ke + 4);
    float cm[8] = {ga.x, ga.y, ga.z, ga.w, gb.x, gb.y, gb.z, gb.w};
    float lamh[8], lamt[8], ec[8], e2[8];
#pragma unroll
    for (int j = 0; j < 8; j++) {
      float cs   = cumsum16(cm[j]);                 // inclusive cumg over t
      float cmid = swzf<(7 << 5) | 0x10>(cs);       // c = cumg at t=7
      lamh[j] = __expf(cs - cmid);
      lamt[j] = __expf(cmid - cs);
      ec[j]   = __expf(cmid);
      e2[j]   = swzf<(15 << 5) | 0x10>(lamh[j]);    // exp(cumg15 - c)
    }
    if (tl == 0) {
#pragma unroll
      for (int j = 0; j < 8; j++) {
        eclds[kb * 32 + gr * 8 + j] = ec[j];
        e2lds[kb * 32 + gr * 8 + j] = e2[j];
      }
    }
    uint4 kr = *(const uint4*)(kn + rowoff + ke);
    uint4 qr = *(const uint4*)(qn + rowoff + ke);
    float kf[8], qf[8];
    { floatx2 a0 = bfpair(kr.x), a1 = bfpair(kr.y), a2 = bfpair(kr.z), a3 = bfpair(kr.w);
      kf[0]=a0[0];kf[1]=a0[1];kf[2]=a1[0];kf[3]=a1[1];kf[4]=a2[0];kf[5]=a2[1];kf[6]=a3[0];kf[7]=a3[1];
      floatx2 b0 = bfpair(qr.x), b1 = bfpair(qr.y), b2 = bfpair(qr.z), b3 = bfpair(qr.w);
      qf[0]=b0[0];qf[1]=b0[1];qf[2]=b1[0];qf[3]=b1[1];qf[4]=b2[0];qf[5]=b2[1];qf[6]=b3[0];qf[7]=b3[1]; }
    bf16x8 khat, ktil, qhat;
#pragma unroll
    for (int j = 0; j < 8; j++) {
      khat[j] = (bf16_t)(kf[j] * lamh[j]);
      ktil[j] = (bf16_t)(kf[j] * lamt[j]);
      qhat[j] = (bf16_t)(qf[j] * lamh[j]);
      khs[kb][j] = (bf16_t)(kf[j] * lamh[j] * ec[j]);   // k * exp(cumg)
      qhs[kb][j] = (bf16_t)(qf[j] * lamh[j] * ec[j]);
    }
    wt = __builtin_amdgcn_mfma_f32_16x16x32_bf16(ktil, khat, wt, 0, 0, 0);  // W^T
    m  = __builtin_amdgcn_mfma_f32_16x16x32_bf16(qhat, ktil, m,  0, 0, 0);  // M
#pragma unroll
    for (int j = 0; j < 8; j++) KldsT[kb * 32 + gr * 8 + j][tl] = ktil[j];
  }
  // in-place khs/qhs stores (all reads of this slice completed above)
#pragma unroll
  for (int kb = 0; kb < 4; kb++) {
    *(uint4*)(kn + rowoff + kb0 + kb * 32) = __builtin_bit_cast(uint4, khs[kb]);
    *(uint4*)(qn + rowoff + kb0 + kb * 32) = __builtin_bit_cast(uint4, qhs[kb]);
  }
  // W, masked M to LDS
#pragma unroll
  for (int ri = 0; ri < 4; ri++) {
    Wlds[tl][4 * gr + ri] = wt[ri];                               // W[t=tl][s=4gr+ri]
    Mlds[4 * gr + ri][tl] = (4 * gr + ri >= tl) ? m[ri] : 0.f;    // M[t][s], tril incl
  }
  // T solve (exact f32): X = inv(I + tril_strict(diag(b)W)); T[t][j] = X[t][j]*b_j
  {
    const int j = tl;
    float x[16];
#pragma unroll
    for (int t = 0; t < 16; t++) {
      float a = 0.f;
#pragma unroll
      for (int s = 0; s < 16; s++)
        if (s < t) a = fmaf(Wlds[t][s], x[s], a);
      x[t] = (t == j) ? 1.f : ((t > j) ? -blds[t] * a : 0.f);
    }
    if (gr == 0) {
      const float bj = blds[j];
#pragma unroll
      for (int t = 0; t < 16; t++)
        Tm[((size_t)hc * 16 + t) * 16 + j] = x[t] * bj;
    }
  }
  // masked-M as ready B-frag (col=t=tl, elems s=gr*8+jj; gr>=2 zero)
  {
    uint4 mbo = {0, 0, 0, 0};
    if (gr < 2) {
      bf16x8 mm;
#pragma unroll
      for (int jj = 0; jj < 8; jj++) mm[jj] = (bf16_t)Mlds[tl][gr * 8 + jj];
      mbo = __builtin_bit_cast(uint4, mm);
    }
    ((uint4*)MBf)[(size_t)hc * 64 + l] = mbo;
  }
  // ktil^T -> global (coalesced rows of 16 bf16)
  for (int i = l; i < 128; i += 64) {
    uint4 a0 = *(const uint4*)&KldsT[i][0];
    uint4 a1 = *(const uint4*)&KldsT[i][8];
    bf16_t* dst = ktilT + ((size_t)hc * 128 + i) * 16;
    *(uint4*)dst = a0;
    *(uint4*)(dst + 8) = a1;
  }
  // ec/e2 transposed for float4 loads: [tl][kt]
  for (int i = l; i < 128; i += 64) {
    ecT[(size_t)hc * 128 + (i & 15) * 8 + (i >> 4)] = eclds[i];
    e2T[(size_t)hc * 128 + (i & 15) * 8 + (i >> 4)] = e2lds[i];
  }
}

// ---------------- serial WY scan, wave-specialized producer/consumer ----------------
// Round-11 change: the consumer no longer touches global memory — its O output
// goes to LDS (sO), and the PRODUCER global-stores the previous chunk's O.
// Rationale: compiler drains vmcnt(0) before every s_barrier; the consumer's
// O-store ack (~300-500cy) sat on the serial chain every chunk. Producer has
// slack. Handoff race-free: O_c written to sO[c&1] at iter c (pre-barrier),
// read by producer at iter c+1, overwritten at iter c+2 (barrier-separated).
__global__ __launch_bounds__(128, 1) void scan_wy3(
    const bf16_t* __restrict__ khsG, const bf16_t* __restrict__ qhsG,
    const bf16_t* __restrict__ vn, const bf16_t* __restrict__ ktilT,
    const float* __restrict__ Tm, const bf16_t* __restrict__ MBf,
    const float* __restrict__ ecT, const float* __restrict__ e2T,
    float* __restrict__ o) {
  const int h   = blockIdx.x >> 3;   // 16 heads
  const int vt  = blockIdx.x & 7;    // 8 v-tiles
  const int tid = threadIdx.x;
  const int wid = tid >> 6;          // 0 = consumer, 1 = producer
  const int l   = tid & 63;
  const int tl  = l & 15;
  const int gr  = l >> 4;

  __shared__ uint4   sKQ[2][8][64];   // khs kb0..3, qhs kb0..3  (16 KiB)
  __shared__ floatx4 sT[2][4][64];    // T rows                   (8 KiB)
  __shared__ uint4   sMB[2][64];      // masked-M B-frag          (2 KiB)
  __shared__ uint4   sKT[2][8][64];   // ktil B-frags             (16 KiB)
  __shared__ floatx4 sEC[2][4][64];   // ec0,ec1,e20,e21          (8 KiB)
  __shared__ uint2   sV[2][64];       // v                        (1 KiB)
  __shared__ float4  sO[2][64];       // O staging (handoff)      (2 KiB)
  __shared__ float   SldsT[16][132];  // S^T [v][k]               (8.25 KiB)
  __shared__ float   DVlds[16][17];   // V' then dv [t][v]

  const int kb0 = h * DH + gr * 8;
  const int vb0 = h * DH + vt * 16 + gr * 4;
  const size_t hcBase = (size_t)h * NCH;
  constexpr float scale = 0.08838834764831845f;

  auto produce = [&](int c, int b) {
    const size_t rowoff = (size_t)(c * CHUNK + tl) * CH;
    const size_t hc = hcBase + c;
    uint4 kq[8];
#pragma unroll
    for (int kb = 0; kb < 4; kb++) {
      kq[kb]     = *(const uint4*)(khsG + rowoff + kb0 + kb * 32);
      kq[4 + kb] = *(const uint4*)(qhsG + rowoff + kb0 + kb * 32);
    }
    const float* Trp = Tm + (hc * 16 + tl) * 16;
    floatx4 Tv[4];
#pragma unroll
    for (int j = 0; j < 4; j++) Tv[j] = *(const floatx4*)(Trp + 4 * j);
    uint4 mbv = ((const uint4*)MBf)[hc * 64 + l];
    const int g2 = gr & 1;
    uint4 ktv[8];
#pragma unroll
    for (int kt = 0; kt < 8; kt++)
      ktv[kt] = *(const uint4*)(ktilT + (hc * 128 + kt * 16 + tl) * 16 + g2 * 8);
    floatx4 ecv[4];
    ecv[0] = *(const floatx4*)(ecT + hc * 128 + tl * 8);
    ecv[1] = *(const floatx4*)(ecT + hc * 128 + tl * 8 + 4);
    ecv[2] = *(const floatx4*)(e2T + hc * 128 + tl * 8);
    ecv[3] = *(const floatx4*)(e2T + hc * 128 + tl * 8 + 4);
    uint2 vv = *(const uint2*)(vn + rowoff + vb0);
#pragma unroll
    for (int i = 0; i < 8; i++) sKQ[b][i][l] = kq[i];
#pragma unroll
    for (int j = 0; j < 4; j++) sT[b][j][l] = Tv[j];
    sMB[b][l] = mbv;
#pragma unroll
    for (int i = 0; i < 8; i++) sKT[b][i][l] = ktv[i];
#pragma unroll
    for (int j = 0; j < 4; j++) sEC[b][j][l] = ecv[j];
    sV[b][l] = vv;
  };

  float S[8][4];
#pragma unroll
  for (int kt = 0; kt < 8; kt++)
#pragma unroll
    for (int ri = 0; ri < 4; ri++) S[kt][ri] = 0.f;

  if (wid == 1) {
    produce(0, 0);
  } else {
    for (int i = l; i < 16 * 132; i += 64) (&SldsT[0][0])[i] = 0.f;
  }
  __syncthreads();

  int cur = 0;
  for (int c = 0; c < NCH; ++c) {
    if (wid == 1) {
      // store previous chunk's O (written to sO[cur^1] at iter c-1)
      if (c >= 1) {
        float4 ov = sO[cur ^ 1][l];
        const size_t rowp = (size_t)((c - 1) * CHUNK + tl) * CH;
        *(float4*)(o + rowp + vb0) = ov;
      }
      produce(c + 1 < NCH ? c + 1 : NCH - 1, cur ^ 1);
    } else {
      // ---- P, O1 from S0 ----
      floatx4 p  = (floatx4){0.f, 0.f, 0.f, 0.f};
      floatx4 o1 = (floatx4){0.f, 0.f, 0.f, 0.f};
#pragma unroll
      for (int kb = 0; kb < 4; kb++) {
        float4 sa = *(const float4*)(&SldsT[tl][kb * 32 + gr * 8]);
        float4 sb = *(const float4*)(&SldsT[tl][kb * 32 + gr * 8 + 4]);
        bf16x8 s0a;
        s0a[0]=(bf16_t)sa.x; s0a[1]=(bf16_t)sa.y; s0a[2]=(bf16_t)sa.z; s0a[3]=(bf16_t)sa.w;
        s0a[4]=(bf16_t)sb.x; s0a[5]=(bf16_t)sb.y; s0a[6]=(bf16_t)sb.z; s0a[7]=(bf16_t)sb.w;
        p  = __builtin_amdgcn_mfma_f32_16x16x32_bf16(s0a, __builtin_bit_cast(bf16x8, sKQ[cur][kb][l]), p,  0, 0, 0);
        o1 = __builtin_amdgcn_mfma_f32_16x16x32_bf16(s0a, __builtin_bit_cast(bf16x8, sKQ[cur][4 + kb][l]), o1, 0, 0, 0);
      }
      // ---- V' = V - P -> DVlds; DV = T*V' via broadcast LDS reads (exact f32) ----
      float acc[4];
      { uint2 vr = sV[cur][l];
        floatx2 v01 = bfpair(vr.x), v23 = bfpair(vr.y);
        acc[0] = v01[0] - p[0]; acc[1] = v01[1] - p[1];
        acc[2] = v23[0] - p[2]; acc[3] = v23[1] - p[3]; }
      *(float4*)(&DVlds[tl][4 * gr]) = make_float4(acc[0], acc[1], acc[2], acc[3]);
      floatx4 T0 = sT[cur][0][l], T1 = sT[cur][1][l], T2 = sT[cur][2][l], T3 = sT[cur][3][l];
      float dv[4] = {0.f, 0.f, 0.f, 0.f};
#pragma unroll
      for (int s = 0; s < 16; s++) {
        const float ts = (s < 4) ? T0[s] : (s < 8) ? T1[s - 4] : (s < 12) ? T2[s - 8] : T3[s - 12];
        float4 vp = *(const float4*)(&DVlds[s][4 * gr]);   // 16 tl-lanes same addr: broadcast
        dv[0] = fmaf(ts, vp.x, dv[0]);
        dv[1] = fmaf(ts, vp.y, dv[1]);
        dv[2] = fmaf(ts, vp.z, dv[2]);
        dv[3] = fmaf(ts, vp.w, dv[3]);
      }
#pragma unroll
      for (int ri = 0; ri < 4; ri++) DVlds[tl][4 * gr + ri] = dv[ri];
      bf16x8 dva = {};
      if (gr < 2) {
#pragma unroll
        for (int jj = 0; jj < 8; jj++) dva[jj] = (bf16_t)DVlds[gr * 8 + jj][tl];
      }
      // ---- O2; O -> LDS staging (producer stores it next iteration) ----
      floatx4 o2 = __builtin_amdgcn_mfma_f32_16x16x32_bf16(
          dva, __builtin_bit_cast(bf16x8, sMB[cur][l]), (floatx4){0.f, 0.f, 0.f, 0.f}, 0, 0, 0);
      sO[cur][l] = make_float4((o1[0] + o2[0]) * scale, (o1[1] + o2[1]) * scale,
                               (o1[2] + o2[2]) * scale, (o1[3] + o2[3]) * scale);
      // ---- S update: S' = e2*(ec*S0 + DV^T K~) ----
      floatx4 ec0 = sEC[cur][0][l], ec1 = sEC[cur][1][l];
      floatx4 e20 = sEC[cur][2][l], e21 = sEC[cur][3][l];
#pragma unroll
      for (int kt = 0; kt < 8; kt++) {
        const float ecK = (kt < 4) ? ec0[kt] : ec1[kt - 4];
        const float e2K = (kt < 4) ? e20[kt] : e21[kt - 4];
        floatx4 sa;
#pragma unroll
        for (int ri = 0; ri < 4; ri++) sa[ri] = ecK * S[kt][ri];
        sa = __builtin_amdgcn_mfma_f32_16x16x32_bf16(
            dva, __builtin_bit_cast(bf16x8, sKT[cur][kt][l]), sa, 0, 0, 0);
#pragma unroll
        for (int ri = 0; ri < 4; ri++) S[kt][ri] = e2K * sa[ri];
      }
      // ---- publish S^T for next chunk ----
#pragma unroll
      for (int kt = 0; kt < 8; kt++)
#pragma unroll
        for (int ri = 0; ri < 4; ri++)
          SldsT[4 * gr + ri][kt * 16 + tl] = S[kt][ri];
    }
    __syncthreads();
    cur ^= 1;
  }
  // epilogue: store the final chunk's O (in sO[(NCH-1)&1], written pre-barrier)
  if (wid == 1) {
    float4 ov = sO[(NCH - 1) & 1][l];
    const size_t rowp = (size_t)((NCH - 1) * CHUNK + tl) * CH;
    *(float4*)(o + rowp + vb0) = ov;
  }
}

// ---------------- postprocess: RMSNorm * norm_w * silu(gate bf16) -> bf16 ----------------
__global__ __launch_bounds__(256) void postprocess(
    const float* __restrict__ o, const bf16_t* __restrict__ gate,
    const float* __restrict__ norm_w, bf16_t* __restrict__ og) {
  const int t = blockIdx.x, tid = threadIdx.x;
  const int c0 = tid * 8, d0 = c0 & 127;
  const size_t o0 = (size_t)t * CH + c0;
  float ov[8], gv[8], nw[8];
  { float4 a = *(const float4*)(o + o0);    float4 b = *(const float4*)(o + o0 + 4);
    ov[0]=a.x; ov[1]=a.y; ov[2]=a.z; ov[3]=a.w; ov[4]=b.x; ov[5]=b.y; ov[6]=b.z; ov[7]=b.w;
    bf16x8 g8 = *(const bf16x8*)(gate + o0);
    for (int j = 0; j < 8; j++) gv[j] = (float)g8[j];
    float4 e = *(const float4*)(norm_w + d0); float4 f = *(const float4*)(norm_w + d0 + 4);
    nw[0]=e.x; nw[1]=e.y; nw[2]=e.z; nw[3]=e.w; nw[4]=f.x; nw[5]=f.y; nw[6]=f.z; nw[7]=f.w; }
  float ss = 0.f;
#pragma unroll
  for (int j = 0; j < 8; j++) ss += ov[j] * ov[j];
#pragma unroll
  for (int m = 1; m < 16; m <<= 1) ss += __shfl_xor(ss, m);
  const float rs = rsqrtf(ss * (1.f / 128.f) + 1e-6f);
  bf16x8 r;
#pragma unroll
  for (int j = 0; j < 8; j++) {
    float g = gv[j];
    float val = ov[j] * rs * nw[j] * (g / (1.f + expf(-g)));
    r[j] = (bf16_t)val;
  }
  *(bf16x8*)(og + o0) = r;
}

// ---------------- host launcher ----------------
static inline void launch_gemm(const bf16_t* A, int lda, const bf16_t* Bt, int ldb,
                               void* C, int ldc, int M, int N, int K, bool obf16,
                               hipStream_t s) {
  dim3 grid(M / 128, (N + 127) / 128);
  if ((N & 127) == 0) {
    if (obf16) gemm_bf16_lds<true><<<grid, 256, 0, s>>>(A, lda, Bt, ldb, C, ldc, M, N, K);
    else       gemm_bf16_lds<false><<<grid, 256, 0, s>>>(A, lda, Bt, ldb, C, ldc, M, N, K);
  } else {
    if (obf16) gemm_bf16<true><<<grid, 256, 0, s>>>(A, lda, Bt, ldb, C, ldc, M, N, K);
    else       gemm_bf16<false><<<grid, 256, 0, s>>>(A, lda, Bt, ldb, C, ldc, M, N, K);
  }
}

extern "C" void kernel_launch(void* const* d_in, const int* in_sizes, int n_in,
                              void* d_out, int out_size, void* d_ws, size_t ws_size,
                              hipStream_t stream) {
  const float* x       = (const float*)d_in[0];
  const float* Wq      = (const float*)d_in[1];
  const float* Wk      = (const float*)d_in[2];
  const float* Wv      = (const float*)d_in[3];
  const float* wqc     = (const float*)d_in[4];
  const float* wkc     = (const float*)d_in[5];
  const float* wvc     = (const float*)d_in[6];
  const float* A_log   = (const float*)d_in[7];
  const float* dt_bias = (const float*)d_in[8];
  const float* Wfa     = (const float*)d_in[9];
  const float* Wfb     = (const float*)d_in[10];
  const float* Wb      = (const float*)d_in[11];
  const float* Wga     = (const float*)d_in[12];
  const float* Wgb     = (const float*)d_in[13];
  const float* norm_w  = (const float*)d_in[14];
  const float* Wo      = (const float*)d_in[15];

  char* w = (char*)d_ws;
  size_t off = 0;
  auto give = [&](size_t bytes) -> void* {
    size_t cur = off;
    off = (off + bytes + 255) & ~(size_t)255;
    return (void*)(w + cur);
  };
  bf16_t* Wbig = (bf16_t*)give((size_t)CH * HID * 2);   // reused: WqT,WkT,WvT,WoT
  bf16_t* WfgT = (bf16_t*)give((size_t)256 * HID * 2);  // [WfaT; WgaT] rows 0..255
  bf16_t* WfbT = (bf16_t*)give((size_t)CH * 128 * 2);
  bf16_t* WgbT = (bf16_t*)give((size_t)CH * 128 * 2);
  bf16_t* WbT  = (bf16_t*)give((size_t)NH * HID * 2);
  bf16_t* Ax   = (bf16_t*)give((size_t)T_TOK * HID * 2);  // 16 MiB
  bf16_t* raw0 = (bf16_t*)give((size_t)T_TOK * CH * 2);   // 16 MiB, reused q/k/v raw
  bf16_t* qnb  = (bf16_t*)give((size_t)T_TOK * CH * 2);
  bf16_t* knb  = (bf16_t*)give((size_t)T_TOK * CH * 2);
  bf16_t* vnb  = (bf16_t*)give((size_t)T_TOK * CH * 2);
  bf16_t* f1g1 = (bf16_t*)give((size_t)T_TOK * 256 * 2);  // f1 cols 0..127, g1 cols 128..255
  float*  fbuf = (float*)give((size_t)T_TOK * CH * 4);    // f_pre -> g (log decay) in-place
  bf16_t* gateb= (bf16_t*)give((size_t)T_TOK * CH * 2);
  float*  betab= (float*)give((size_t)T_TOK * NH * 4);
  // WY precompute buffers (+28 MiB)
  bf16_t* ktilT= (bf16_t*)give((size_t)NH * NCH * 128 * 16 * 2);  // 16 MiB
  float*  Tmat = (float*)give((size_t)NH * NCH * 256 * 4);        // 4 MiB
  bf16_t* MBf  = (bf16_t*)give((size_t)NH * NCH * 64 * 8 * 2);    // 4 MiB
  float*  ecTb = (float*)give((size_t)NH * NCH * 128 * 4);        // 2 MiB
  float*  e2Tb = (float*)give((size_t)NH * NCH * 128 * 4);        // 2 MiB
  // aliases over dead regions:
  float*  obuf = (float*)Ax;    // 32 MiB = Ax(16)+raw0(16), both dead before scan
  bf16_t* ogb  = qnb;           // qnb dead after scan

  auto tr = [&](const float* in, bf16_t* out, int R, int C) {
    transpose_cast<<<dim3((R + 31) / 32, (C + 31) / 32), 256, 0, stream>>>(in, out, R, C);
  };

  // 1) cast x, small weight transposes
  cast_to_bf16<<<dim3((T_TOK * HID) / 2048), 256, 0, stream>>>(x, Ax, T_TOK * HID);
  tr(Wfa, WfgT, HID, 128);                 // rows 0..127
  tr(Wga, WfgT + (size_t)128 * HID, HID, 128);  // rows 128..255
  tr(Wfb, WfbT, 128, CH);  tr(Wgb, WgbT, 128, CH);
  tr(Wb, WbT, HID, NH);

  // 2) q/k/v: transpose weight -> GEMM -> conv+silu(+l2norm), reusing Wbig and raw0
  tr(Wq, Wbig, HID, CH);
  launch_gemm(Ax, HID, Wbig, HID, raw0, CH, T_TOK, CH, HID, true, stream);
  conv_silu<true><<<dim3(T_TOK), 256, 0, stream>>>(raw0, wqc, qnb);
  tr(Wk, Wbig, HID, CH);
  launch_gemm(Ax, HID, Wbig, HID, raw0, CH, T_TOK, CH, HID, true, stream);
  conv_silu<true><<<dim3(T_TOK), 256, 0, stream>>>(raw0, wkc, knb);
  tr(Wv, Wbig, HID, CH);
  launch_gemm(Ax, HID, Wbig, HID, raw0, CH, T_TOK, CH, HID, true, stream);
  conv_silu<false><<<dim3(T_TOK), 256, 0, stream>>>(raw0, wvc, vnb);

  // 3) f/g/beta chains (f and g first-stage merged: N=256, one launch)
  launch_gemm(Ax, HID, WfgT, HID, f1g1, 256, T_TOK, 256, HID, true, stream);
  launch_gemm(Ax, HID, WbT, HID, betab, NH, T_TOK, NH, HID, false, stream);
  launch_gemm(f1g1, 256, WfbT, 128, fbuf, CH, T_TOK, CH, 128, false, stream);
  launch_gemm(f1g1 + 128, 256, WgbT, 128, gateb, CH, T_TOK, CH, 128, true, stream);
  gamma_beta<<<dim3(T_TOK), 256, 0, stream>>>(fbuf, dt_bias, A_log, betab);

  // 4a) parallel WY prep: 4096 blocks (head x chunk)
  wy_prep<<<dim3(NH * NCH), 64, 0, stream>>>(qnb, knb, fbuf, betab,
                                             ktilT, Tmat, MBf, ecTb, e2Tb);
  // 4b) serial WY scan: 128 blocks (head x v-tile) x 2 waves (compute + producer)
  scan_wy3<<<dim3(128), 128, 0, stream>>>(knb, qnb, vnb, ktilT, Tmat, MBf,
                                          ecTb, e2Tb, obuf);

  // 5) gated RMSNorm -> bf16 (ogb aliases qnb)
  postprocess<<<dim3(T_TOK), 256, 0, stream>>>(obuf, gateb, norm_w, ogb);

  // 6) output projection
  tr(Wo, Wbig, CH, HID);
  launch_gemm(ogb, CH, Wbig, CH, (float*)d_out, HID, T_TOK, HID, CH, false, stream);
}